// Round 1
// baseline (1758.131 us; speedup 1.0000x reference)
//
#include <hip/hip_runtime.h>
#include <hip/hip_bf16.h>
#include <math.h>

#define NEG_SLOPE 0.2f
#define BN_EPS 1e-5f

// ---- order-preserving float<->uint encoding for atomicMax on floats ----
__device__ __forceinline__ unsigned enc_f32(float f) {
    unsigned u = __float_as_uint(f);
    return (u & 0x80000000u) ? ~u : (u | 0x80000000u);
}
__device__ __forceinline__ float dec_f32(unsigned u) {
    unsigned b = (u & 0x80000000u) ? (u ^ 0x80000000u) : ~u;
    return __uint_as_float(b);
}

// ---------------- fp32 tiled GEMM: C[M,NC] = A[M,K] @ B[K,NC] ----------------
// BM=BN=64, BK=16, 256 threads, 4x4 micro-tile per thread.
__global__ __launch_bounds__(256) void gemm64(const float* __restrict__ A,
                                              const float* __restrict__ B,
                                              float* __restrict__ C,
                                              int M, int K, int NC) {
    __shared__ float As[16][68];
    __shared__ float Bs[16][68];
    const int tid = threadIdx.x;
    const int bm = blockIdx.y * 64;
    const int bn = blockIdx.x * 64;
    const int ty = tid >> 4;          // 0..15
    const int tx = tid & 15;          // 0..15
    const int ar = tid >> 2;          // 0..63  (A tile row)
    const int ac = (tid & 3) << 2;    // 0,4,8,12 (A tile col group)
    const int br = tid >> 4;          // 0..15  (B tile row)
    const int bc = (tid & 15) << 2;   // 0..60  (B tile col group)
    float acc[4][4] = {};
    for (int k0 = 0; k0 < K; k0 += 16) {
        float4 av = make_float4(0.f, 0.f, 0.f, 0.f);
        if (bm + ar < M)
            av = *(const float4*)(A + (size_t)(bm + ar) * K + k0 + ac);
        As[ac + 0][ar] = av.x;
        As[ac + 1][ar] = av.y;
        As[ac + 2][ar] = av.z;
        As[ac + 3][ar] = av.w;
        float4 bv = *(const float4*)(B + (size_t)(k0 + br) * NC + bn + bc);
        *(float4*)&Bs[br][bc] = bv;
        __syncthreads();
#pragma unroll
        for (int kk = 0; kk < 16; ++kk) {
            float a[4], b[4];
#pragma unroll
            for (int i = 0; i < 4; ++i) a[i] = As[kk][ty * 4 + i];
#pragma unroll
            for (int j = 0; j < 4; ++j) b[j] = Bs[kk][tx * 4 + j];
#pragma unroll
            for (int i = 0; i < 4; ++i)
#pragma unroll
                for (int j = 0; j < 4; ++j)
                    acc[i][j] = fmaf(a[i], b[j], acc[i][j]);
        }
        __syncthreads();
    }
#pragma unroll
    for (int i = 0; i < 4; ++i) {
        int row = bm + ty * 4 + i;
        if (row < M) {
            float4 v = make_float4(acc[i][0], acc[i][1], acc[i][2], acc[i][3]);
            *(float4*)(C + (size_t)row * NC + bn + tx * 4) = v;
        }
    }
}

// ---------------- CSR build ----------------
__global__ void count_deg(const int* __restrict__ ei, int E, int Etot,
                          int* __restrict__ deg) {
    int e = blockIdx.x * blockDim.x + threadIdx.x;
    if (e >= Etot) return;
    int d = (e < E) ? ei[E + e] : (e - E);   // self-loop for e >= E
    atomicAdd(&deg[d], 1);
}

__global__ __launch_bounds__(1024) void scan_excl(const int* __restrict__ deg,
                                                  int* __restrict__ rowptr, int n) {
    __shared__ int buf[1024];
    int t = threadIdx.x;
    int carry = 0;
    for (int base = 0; base < n; base += 1024) {
        int i = base + t;
        int v = (i < n) ? deg[i] : 0;
        buf[t] = v;
        __syncthreads();
#pragma unroll
        for (int off = 1; off < 1024; off <<= 1) {
            int xv = (t >= off) ? buf[t - off] : 0;
            __syncthreads();
            buf[t] += xv;
            __syncthreads();
        }
        if (i < n) rowptr[i] = carry + buf[t] - v;
        carry += buf[1023];
        __syncthreads();
    }
    if (t == 0) rowptr[n] = carry;
}

__global__ void fill_csr(const int* __restrict__ ei, int E, int Etot,
                         const int* __restrict__ rowptr, int* __restrict__ cursor,
                         int* __restrict__ csrc, int* __restrict__ ceid) {
    int e = blockIdx.x * blockDim.x + threadIdx.x;
    if (e >= Etot) return;
    int s, d;
    if (e < E) { s = ei[e]; d = ei[E + e]; }
    else       { s = e - E; d = s; }
    int pos = rowptr[d] + atomicAdd(&cursor[d], 1);
    csrc[pos] = s;
    ceid[pos] = e;
}

// ---------------- edge logits + segment max ----------------
// One 64-lane wave per edge. C = total channels (H * hid), lane covers C/64 chans.
template <int C, int H>
__global__ __launch_bounds__(256) void edge_logits(
        const float* __restrict__ XL, const float* __restrict__ XR,
        const int* __restrict__ ei, int E, int Etot,
        const float* __restrict__ att,
        float* __restrict__ LOG, unsigned int* __restrict__ Menc) {
    constexpr int CPL = C / 64;
    constexpr int HIDc = C / H;
    constexpr int LPH = 64 / H;
    int wave = (blockIdx.x * blockDim.x + threadIdx.x) >> 6;
    int lane = threadIdx.x & 63;
    if (wave >= Etot) return;
    int s, d;
    if (wave < E) { s = ei[wave]; d = ei[E + wave]; }
    else          { s = wave - E; d = s; }
    int ch0 = lane * CPL;
    const float* xl = XL + (size_t)s * C + ch0;
    const float* xr = XR + (size_t)d * C + ch0;
    float partial = 0.f;
#pragma unroll
    for (int j = 0; j < CPL; ++j) {
        float v = xl[j] + xr[j];
        v = v > 0.f ? v : NEG_SLOPE * v;
        partial = fmaf(v, att[ch0 + j], partial);
    }
#pragma unroll
    for (int off = 1; off < LPH; off <<= 1)
        partial += __shfl_xor(partial, off, 64);
    if ((lane & (LPH - 1)) == 0) {
        int head = ch0 / HIDc;
        LOG[(size_t)wave * H + head] = partial;
        atomicMax(&Menc[(size_t)d * H + head], enc_f32(partial));
    }
}

// ---------------- per-node softmax + aggregate (CSR, no fp32 atomics) -------
template <int C, int H>
__global__ __launch_bounds__(256) void node_agg(
        const float* __restrict__ XL, const float* __restrict__ LOG,
        const unsigned int* __restrict__ Menc,
        const int* __restrict__ rowptr, const int* __restrict__ csrc,
        const int* __restrict__ ceid, const float* __restrict__ bias,
        float* __restrict__ OUT, int N) {
    constexpr int CPL = C / 64;
    constexpr int HIDc = C / H;
    int node = (blockIdx.x * blockDim.x + threadIdx.x) >> 6;
    int lane = threadIdx.x & 63;
    if (node >= N) return;
    int ch0 = lane * CPL;
    int head = ch0 / HIDc;
    float m = dec_f32(Menc[(size_t)node * H + head]);
    float acc[CPL];
#pragma unroll
    for (int j = 0; j < CPL; ++j) acc[j] = 0.f;
    float sumw = 0.f;
    const int e1 = rowptr[node + 1];
    for (int k = rowptr[node]; k < e1; ++k) {
        int s = csrc[k];
        float w = __expf(LOG[(size_t)ceid[k] * H + head] - m);
        sumw += w;
        const float* xl = XL + (size_t)s * C + ch0;
#pragma unroll
        for (int j = 0; j < CPL; ++j) acc[j] = fmaf(w, xl[j], acc[j]);
    }
    float inv = 1.f / sumw;
#pragma unroll
    for (int j = 0; j < CPL; ++j)
        OUT[(size_t)node * C + ch0 + j] = acc[j] * inv + bias[ch0 + j];
}

// ---------------- batchnorm ----------------
__global__ __launch_bounds__(256) void bn_stats(const float* __restrict__ Hm,
        float* __restrict__ sums, float* __restrict__ sqs, int N, int C) {
    int ch = threadIdx.x;               // C == 256 == blockDim.x
    int r0 = blockIdx.x * 256;
    int r1 = min(N, r0 + 256);
    float s = 0.f, q = 0.f;
    for (int r = r0; r < r1; ++r) {
        float v = Hm[(size_t)r * C + ch];
        s += v;
        q = fmaf(v, v, q);
    }
    atomicAdd(&sums[ch], s);
    atomicAdd(&sqs[ch], q);
}

__global__ __launch_bounds__(256) void bn_elu(float* __restrict__ Hm,
        const float* __restrict__ sums, const float* __restrict__ sqs,
        const float* __restrict__ gamma, const float* __restrict__ beta,
        int total, int C, float invN) {
    int idx = blockIdx.x * 256 + threadIdx.x;
    if (idx >= total) return;
    int ch = idx & (C - 1);
    float mu = sums[ch] * invN;
    float var = sqs[ch] * invN - mu * mu;
    float sc = gamma[ch] * rsqrtf(var + BN_EPS);
    float v = (Hm[idx] - mu) * sc + beta[ch];
    Hm[idx] = v > 0.f ? v : expm1f(v);
}

extern "C" void kernel_launch(void* const* d_in, const int* in_sizes, int n_in,
                              void* d_out, int out_size, void* d_ws, size_t ws_size,
                              hipStream_t stream) {
    const float* x    = (const float*)d_in[0];
    const int*   ei   = (const int*)d_in[1];
    const float* Wl1  = (const float*)d_in[2];
    const float* Wr1  = (const float*)d_in[3];
    const float* att1 = (const float*)d_in[4];
    const float* b1   = (const float*)d_in[5];
    const float* g1   = (const float*)d_in[6];
    const float* be1  = (const float*)d_in[7];
    const float* Wl2  = (const float*)d_in[8];
    const float* Wr2  = (const float*)d_in[9];
    const float* att2 = (const float*)d_in[10];
    const float* b2   = (const float*)d_in[11];
    const float* g2   = (const float*)d_in[12];
    const float* be2  = (const float*)d_in[13];
    const float* Wl3  = (const float*)d_in[14];
    const float* Wr3  = (const float*)d_in[15];
    const float* att3 = (const float*)d_in[16];
    const float* b3   = (const float*)d_in[17];
    float* out = (float*)d_out;

    const int IN_F = 128, HC = 256, OUT_F = 128;
    const int N = in_sizes[0] / IN_F;     // 50000
    const int E = in_sizes[1] / 2;        // 800000
    const int Etot = E + N;               // 850000

    // ---- workspace carve-up (all offsets 256B aligned) ----
    char* p = (char*)d_ws;
    auto alloc = [&](size_t bytes) {
        void* r = (void*)p;
        p += (bytes + 255) & ~(size_t)255;
        return r;
    };
    float* XL      = (float*)alloc((size_t)N * HC * 4);
    float* XR      = (float*)alloc((size_t)N * HC * 4);
    float* Hb      = (float*)alloc((size_t)N * HC * 4);
    float* LOG     = (float*)alloc((size_t)Etot * 4 * 4);
    unsigned* Menc = (unsigned*)alloc((size_t)N * 4 * 4);
    int* deg       = (int*)alloc((size_t)N * 4);
    int* rowptr    = (int*)alloc((size_t)(N + 1) * 4);
    int* cursor    = (int*)alloc((size_t)N * 4);
    int* csrc      = (int*)alloc((size_t)Etot * 4);
    int* ceid      = (int*)alloc((size_t)Etot * 4);
    float* bns     = (float*)alloc((size_t)HC * 4);
    float* bnq     = (float*)alloc((size_t)HC * 4);

    const int eb = (Etot + 255) / 256;       // edge-parallel blocks
    const int wb = (Etot + 3) / 4;           // wave-per-edge blocks (4 waves/block)
    const int nb = (N + 3) / 4;              // wave-per-node blocks
    const int gemmRows = (N + 63) / 64;

    // ---- CSR by dst (built once, reused by all 3 layers) ----
    hipMemsetAsync(deg, 0, (size_t)N * 4, stream);
    count_deg<<<eb, 256, 0, stream>>>(ei, E, Etot, deg);
    scan_excl<<<1, 1024, 0, stream>>>(deg, rowptr, N);
    hipMemsetAsync(cursor, 0, (size_t)N * 4, stream);
    fill_csr<<<eb, 256, 0, stream>>>(ei, E, Etot, rowptr, cursor, csrc, ceid);

    // ================= Layer 1 =================
    gemm64<<<dim3(HC / 64, gemmRows), 256, 0, stream>>>(x, Wl1, XL, N, IN_F, HC);
    gemm64<<<dim3(HC / 64, gemmRows), 256, 0, stream>>>(x, Wr1, XR, N, IN_F, HC);
    hipMemsetAsync(Menc, 0, (size_t)N * 4 * 4, stream);
    edge_logits<256, 4><<<wb, 256, 0, stream>>>(XL, XR, ei, E, Etot, att1, LOG, Menc);
    node_agg<256, 4><<<nb, 256, 0, stream>>>(XL, LOG, Menc, rowptr, csrc, ceid, b1, Hb, N);
    hipMemsetAsync(bns, 0, HC * 4, stream);
    hipMemsetAsync(bnq, 0, HC * 4, stream);
    bn_stats<<<(N + 255) / 256, 256, 0, stream>>>(Hb, bns, bnq, N, HC);
    bn_elu<<<(N * HC + 255) / 256, 256, 0, stream>>>(Hb, bns, bnq, g1, be1, N * HC, HC, 1.f / N);

    // ================= Layer 2 =================
    gemm64<<<dim3(HC / 64, gemmRows), 256, 0, stream>>>(Hb, Wl2, XL, N, HC, HC);
    gemm64<<<dim3(HC / 64, gemmRows), 256, 0, stream>>>(Hb, Wr2, XR, N, HC, HC);
    hipMemsetAsync(Menc, 0, (size_t)N * 4 * 4, stream);
    edge_logits<256, 4><<<wb, 256, 0, stream>>>(XL, XR, ei, E, Etot, att2, LOG, Menc);
    node_agg<256, 4><<<nb, 256, 0, stream>>>(XL, LOG, Menc, rowptr, csrc, ceid, b2, Hb, N);
    hipMemsetAsync(bns, 0, HC * 4, stream);
    hipMemsetAsync(bnq, 0, HC * 4, stream);
    bn_stats<<<(N + 255) / 256, 256, 0, stream>>>(Hb, bns, bnq, N, HC);
    bn_elu<<<(N * HC + 255) / 256, 256, 0, stream>>>(Hb, bns, bnq, g2, be2, N * HC, HC, 1.f / N);

    // ================= Layer 3 (1 head, 128 ch, no concat) =================
    gemm64<<<dim3(OUT_F / 64, gemmRows), 256, 0, stream>>>(Hb, Wl3, XL, N, HC, OUT_F);
    gemm64<<<dim3(OUT_F / 64, gemmRows), 256, 0, stream>>>(Hb, Wr3, XR, N, HC, OUT_F);
    hipMemsetAsync(Menc, 0, (size_t)N * 4, stream);
    edge_logits<128, 1><<<wb, 256, 0, stream>>>(XL, XR, ei, E, Etot, att3, LOG, Menc);
    node_agg<128, 1><<<nb, 256, 0, stream>>>(XL, LOG, Menc, rowptr, csrc, ceid, b3, out, N);
}

// Round 2
// 1068.457 us; speedup vs baseline: 1.6455x; 1.6455x over previous
//
#include <hip/hip_runtime.h>
#include <hip/hip_bf16.h>
#include <math.h>

#define NEG_SLOPE 0.2f
#define BN_EPS 1e-5f

// ---------------- fp32 tiled GEMM: C[M,NC] = A[M,K] @ B[K,NC] ----------------
// BM=BN=64, BK=16, 256 threads, 4x4 micro-tile per thread.
// OutT = float (fp32 store) or __hip_bfloat16 (RNE-converted store).
template <typename OutT>
__global__ __launch_bounds__(256) void gemm64(const float* __restrict__ A,
                                              const float* __restrict__ B,
                                              OutT* __restrict__ C,
                                              int M, int K, int NC) {
    __shared__ float As[16][68];
    __shared__ float Bs[16][68];
    const int tid = threadIdx.x;
    const int bm = blockIdx.y * 64;
    const int bn = blockIdx.x * 64;
    const int ty = tid >> 4;          // 0..15
    const int tx = tid & 15;          // 0..15
    const int ar = tid >> 2;          // 0..63  (A tile row)
    const int ac = (tid & 3) << 2;    // 0,4,8,12 (A tile col group)
    const int br = tid >> 4;          // 0..15  (B tile row)
    const int bc = (tid & 15) << 2;   // 0..60  (B tile col group)
    float acc[4][4] = {};
    for (int k0 = 0; k0 < K; k0 += 16) {
        float4 av = make_float4(0.f, 0.f, 0.f, 0.f);
        if (bm + ar < M)
            av = *(const float4*)(A + (size_t)(bm + ar) * K + k0 + ac);
        As[ac + 0][ar] = av.x;
        As[ac + 1][ar] = av.y;
        As[ac + 2][ar] = av.z;
        As[ac + 3][ar] = av.w;
        float4 bv = *(const float4*)(B + (size_t)(k0 + br) * NC + bn + bc);
        *(float4*)&Bs[br][bc] = bv;
        __syncthreads();
#pragma unroll
        for (int kk = 0; kk < 16; ++kk) {
            float a[4], b[4];
#pragma unroll
            for (int i = 0; i < 4; ++i) a[i] = As[kk][ty * 4 + i];
#pragma unroll
            for (int j = 0; j < 4; ++j) b[j] = Bs[kk][tx * 4 + j];
#pragma unroll
            for (int i = 0; i < 4; ++i)
#pragma unroll
                for (int j = 0; j < 4; ++j)
                    acc[i][j] = fmaf(a[i], b[j], acc[i][j]);
        }
        __syncthreads();
    }
#pragma unroll
    for (int i = 0; i < 4; ++i) {
        int row = bm + ty * 4 + i;
        if (row < M) {
            if constexpr (sizeof(OutT) == 4) {
                float4 v = make_float4(acc[i][0], acc[i][1], acc[i][2], acc[i][3]);
                *(float4*)((float*)C + (size_t)row * NC + bn + tx * 4) = v;
            } else {
                __hip_bfloat16 h[4];
#pragma unroll
                for (int j = 0; j < 4; ++j) h[j] = __float2bfloat16(acc[i][j]);
                *(uint2*)((__hip_bfloat16*)C + (size_t)row * NC + bn + tx * 4) =
                    *(const uint2*)h;
            }
        }
    }
}

// ---------------- CSR build ----------------
__global__ void count_deg(const int* __restrict__ ei, int E, int Etot,
                          int* __restrict__ deg) {
    int e = blockIdx.x * blockDim.x + threadIdx.x;
    if (e >= Etot) return;
    int d = (e < E) ? ei[E + e] : (e - E);   // self-loop for e >= E
    atomicAdd(&deg[d], 1);
}

__global__ __launch_bounds__(1024) void scan_excl(const int* __restrict__ deg,
                                                  int* __restrict__ rowptr, int n) {
    __shared__ int buf[1024];
    int t = threadIdx.x;
    int carry = 0;
    for (int base = 0; base < n; base += 1024) {
        int i = base + t;
        int v = (i < n) ? deg[i] : 0;
        buf[t] = v;
        __syncthreads();
#pragma unroll
        for (int off = 1; off < 1024; off <<= 1) {
            int xv = (t >= off) ? buf[t - off] : 0;
            __syncthreads();
            buf[t] += xv;
            __syncthreads();
        }
        if (i < n) rowptr[i] = carry + buf[t] - v;
        carry += buf[1023];
        __syncthreads();
    }
    if (t == 0) rowptr[n] = carry;
}

__global__ void fill_csr(const int* __restrict__ ei, int E, int Etot,
                         const int* __restrict__ rowptr, int* __restrict__ cursor,
                         int* __restrict__ csrc) {
    int e = blockIdx.x * blockDim.x + threadIdx.x;
    if (e >= Etot) return;
    int s, d;
    if (e < E) { s = ei[e]; d = ei[E + e]; }
    else       { s = e - E; d = s; }
    int pos = rowptr[d] + atomicAdd(&cursor[d], 1);
    csrc[pos] = s;
}

// -------- bf16 row fragment -> fp32 registers --------
template <int CPL>
__device__ __forceinline__ void bload(float* d, const __hip_bfloat16* p) {
    if constexpr (CPL == 4) {
        uint2 u = *(const uint2*)p;
        d[0] = __uint_as_float(u.x << 16);
        d[1] = __uint_as_float(u.x & 0xffff0000u);
        d[2] = __uint_as_float(u.y << 16);
        d[3] = __uint_as_float(u.y & 0xffff0000u);
    } else {
        unsigned u = *(const unsigned*)p;
        d[0] = __uint_as_float(u << 16);
        d[1] = __uint_as_float(u & 0xffff0000u);
    }
}

// ---- fused GATv2 attention + aggregate: one wave per node, online softmax ----
// CSR order by dst; reads each xl[src] row exactly once; no atomics, no LOG.
template <int C, int H>
__global__ __launch_bounds__(256) void gat_agg(
        const __hip_bfloat16* __restrict__ XL,
        const __hip_bfloat16* __restrict__ XR,
        const int* __restrict__ rowptr, const int* __restrict__ csrc,
        const float* __restrict__ att, const float* __restrict__ bias,
        float* __restrict__ OUT, int N) {
    constexpr int CPL = C / 64;
    constexpr int LPH = 64 / H;     // lanes per head
    int node = (blockIdx.x * blockDim.x + threadIdx.x) >> 6;
    int lane = threadIdx.x & 63;
    if (node >= N) return;
    int ch0 = lane * CPL;

    float attv[CPL], xrv[CPL];
    bload<CPL>(xrv, XR + (size_t)node * C + ch0);
#pragma unroll
    for (int j = 0; j < CPL; ++j) attv[j] = att[ch0 + j];

    float m = -INFINITY, sumw = 0.f;
    float acc[CPL];
#pragma unroll
    for (int j = 0; j < CPL; ++j) acc[j] = 0.f;

    const int e0 = rowptr[node], e1 = rowptr[node + 1];  // deg >= 1 (self-loop)
    float nxt[CPL];
    bload<CPL>(nxt, XL + (size_t)csrc[e0] * C + ch0);
    for (int k = e0; k < e1; ++k) {
        float xlv[CPL];
#pragma unroll
        for (int j = 0; j < CPL; ++j) xlv[j] = nxt[j];
        if (k + 1 < e1)                                   // prefetch next src row
            bload<CPL>(nxt, XL + (size_t)csrc[k + 1] * C + ch0);

        float partial = 0.f;
#pragma unroll
        for (int j = 0; j < CPL; ++j) {
            float v = xlv[j] + xrv[j];
            v = v > 0.f ? v : NEG_SLOPE * v;
            partial = fmaf(v, attv[j], partial);
        }
#pragma unroll
        for (int off = 1; off < LPH; off <<= 1)
            partial += __shfl_xor(partial, off, 64);
        float l = partial;                                // head logit (uniform in group)

        // branchless online-softmax update
        float mn = fmaxf(m, l);
        float wl = __expf(l - mn);                        // weight of this edge
        float rm = __expf(m - mn);                        // rescale of history
        sumw = fmaf(sumw, rm, wl);
#pragma unroll
        for (int j = 0; j < CPL; ++j)
            acc[j] = fmaf(acc[j], rm, wl * xlv[j]);
        m = mn;
    }
    float inv = 1.f / sumw;
#pragma unroll
    for (int j = 0; j < CPL; ++j)
        OUT[(size_t)node * C + ch0 + j] = fmaf(acc[j], inv, bias[ch0 + j]);
}

// ---------------- batchnorm ----------------
__global__ __launch_bounds__(256) void bn_stats(const float* __restrict__ Hm,
        float* __restrict__ sums, float* __restrict__ sqs, int N, int C) {
    int ch = threadIdx.x;               // C == 256 == blockDim.x
    int r0 = blockIdx.x * 256;
    int r1 = min(N, r0 + 256);
    float s = 0.f, q = 0.f;
    for (int r = r0; r < r1; ++r) {
        float v = Hm[(size_t)r * C + ch];
        s += v;
        q = fmaf(v, v, q);
    }
    atomicAdd(&sums[ch], s);
    atomicAdd(&sqs[ch], q);
}

__global__ __launch_bounds__(256) void bn_elu(float* __restrict__ Hm,
        const float* __restrict__ sums, const float* __restrict__ sqs,
        const float* __restrict__ gamma, const float* __restrict__ beta,
        int total, int C, float invN) {
    int idx = blockIdx.x * 256 + threadIdx.x;
    if (idx >= total) return;
    int ch = idx & (C - 1);
    float mu = sums[ch] * invN;
    float var = sqs[ch] * invN - mu * mu;
    float sc = gamma[ch] * rsqrtf(var + BN_EPS);
    float v = (Hm[idx] - mu) * sc + beta[ch];
    Hm[idx] = v > 0.f ? v : expm1f(v);
}

extern "C" void kernel_launch(void* const* d_in, const int* in_sizes, int n_in,
                              void* d_out, int out_size, void* d_ws, size_t ws_size,
                              hipStream_t stream) {
    const float* x    = (const float*)d_in[0];
    const int*   ei   = (const int*)d_in[1];
    const float* Wl1  = (const float*)d_in[2];
    const float* Wr1  = (const float*)d_in[3];
    const float* att1 = (const float*)d_in[4];
    const float* b1   = (const float*)d_in[5];
    const float* g1   = (const float*)d_in[6];
    const float* be1  = (const float*)d_in[7];
    const float* Wl2  = (const float*)d_in[8];
    const float* Wr2  = (const float*)d_in[9];
    const float* att2 = (const float*)d_in[10];
    const float* b2   = (const float*)d_in[11];
    const float* g2   = (const float*)d_in[12];
    const float* be2  = (const float*)d_in[13];
    const float* Wl3  = (const float*)d_in[14];
    const float* Wr3  = (const float*)d_in[15];
    const float* att3 = (const float*)d_in[16];
    const float* b3   = (const float*)d_in[17];
    float* out = (float*)d_out;

    const int IN_F = 128, HC = 256, OUT_F = 128;
    const int N = in_sizes[0] / IN_F;     // 50000
    const int E = in_sizes[1] / 2;        // 800000
    const int Etot = E + N;               // 850000

    // ---- workspace carve-up (all offsets 256B aligned) ----
    char* p = (char*)d_ws;
    auto alloc = [&](size_t bytes) {
        void* r = (void*)p;
        p += (bytes + 255) & ~(size_t)255;
        return r;
    };
    __hip_bfloat16* XL = (__hip_bfloat16*)alloc((size_t)N * HC * 2);
    __hip_bfloat16* XR = (__hip_bfloat16*)alloc((size_t)N * HC * 2);
    float* Hb      = (float*)alloc((size_t)N * HC * 4);
    int* deg       = (int*)alloc((size_t)N * 4);
    int* rowptr    = (int*)alloc((size_t)(N + 1) * 4);
    int* cursor    = (int*)alloc((size_t)N * 4);
    int* csrc      = (int*)alloc((size_t)Etot * 4);
    float* bns     = (float*)alloc((size_t)HC * 4);
    float* bnq     = (float*)alloc((size_t)HC * 4);

    const int eb = (Etot + 255) / 256;       // edge-parallel blocks
    const int nb = (N + 3) / 4;              // wave-per-node blocks
    const int gemmRows = (N + 63) / 64;

    // ---- CSR by dst (built once, reused by all 3 layers) ----
    hipMemsetAsync(deg, 0, (size_t)N * 4, stream);
    count_deg<<<eb, 256, 0, stream>>>(ei, E, Etot, deg);
    scan_excl<<<1, 1024, 0, stream>>>(deg, rowptr, N);
    hipMemsetAsync(cursor, 0, (size_t)N * 4, stream);
    fill_csr<<<eb, 256, 0, stream>>>(ei, E, Etot, rowptr, cursor, csrc);

    // ================= Layer 1 =================
    gemm64<<<dim3(HC / 64, gemmRows), 256, 0, stream>>>(x, Wl1, XL, N, IN_F, HC);
    gemm64<<<dim3(HC / 64, gemmRows), 256, 0, stream>>>(x, Wr1, XR, N, IN_F, HC);
    gat_agg<256, 4><<<nb, 256, 0, stream>>>(XL, XR, rowptr, csrc, att1, b1, Hb, N);
    hipMemsetAsync(bns, 0, HC * 4, stream);
    hipMemsetAsync(bnq, 0, HC * 4, stream);
    bn_stats<<<(N + 255) / 256, 256, 0, stream>>>(Hb, bns, bnq, N, HC);
    bn_elu<<<(N * HC + 255) / 256, 256, 0, stream>>>(Hb, bns, bnq, g1, be1, N * HC, HC, 1.f / N);

    // ================= Layer 2 =================
    gemm64<<<dim3(HC / 64, gemmRows), 256, 0, stream>>>(Hb, Wl2, XL, N, HC, HC);
    gemm64<<<dim3(HC / 64, gemmRows), 256, 0, stream>>>(Hb, Wr2, XR, N, HC, HC);
    gat_agg<256, 4><<<nb, 256, 0, stream>>>(XL, XR, rowptr, csrc, att2, b2, Hb, N);
    hipMemsetAsync(bns, 0, HC * 4, stream);
    hipMemsetAsync(bnq, 0, HC * 4, stream);
    bn_stats<<<(N + 255) / 256, 256, 0, stream>>>(Hb, bns, bnq, N, HC);
    bn_elu<<<(N * HC + 255) / 256, 256, 0, stream>>>(Hb, bns, bnq, g2, be2, N * HC, HC, 1.f / N);

    // ================= Layer 3 (1 head, 128 ch, no concat) =================
    gemm64<<<dim3(OUT_F / 64, gemmRows), 256, 0, stream>>>(Hb, Wl3, XL, N, HC, OUT_F);
    gemm64<<<dim3(OUT_F / 64, gemmRows), 256, 0, stream>>>(Hb, Wr3, XR, N, HC, OUT_F);
    gat_agg<128, 1><<<nb, 256, 0, stream>>>(XL, XR, rowptr, csrc, att3, b3, out, N);
}

// Round 3
// 794.093 us; speedup vs baseline: 2.2140x; 1.3455x over previous
//
#include <hip/hip_runtime.h>
#include <hip/hip_bf16.h>
#include <math.h>

#define NEG_SLOPE 0.2f
#define BN_EPS 1e-5f

using frag  = __attribute__((ext_vector_type(8))) short;   // 8 x bf16
using f32x4 = __attribute__((ext_vector_type(4))) float;

#define GLOAD_LDS16(gp, lp) __builtin_amdgcn_global_load_lds( \
    (const __attribute__((address_space(1))) void*)(gp),      \
    (__attribute__((address_space(3))) void*)(lp), 16, 0, 0)

// ---------------- conversions ----------------
__global__ __launch_bounds__(256) void f32_to_bf16(const float* __restrict__ in,
                                                   __hip_bfloat16* __restrict__ out,
                                                   int n4) {   // n4 = n/4
    int i = blockIdx.x * 256 + threadIdx.x;
    if (i >= n4) return;
    float4 v = *(const float4*)(in + (size_t)i * 4);
    __hip_bfloat16 h[4] = {__float2bfloat16(v.x), __float2bfloat16(v.y),
                           __float2bfloat16(v.z), __float2bfloat16(v.w)};
    *(uint2*)(out + (size_t)i * 4) = *(const uint2*)h;
}

// W[K][N] fp32 -> Wt[N][K] bf16
__global__ __launch_bounds__(256) void transpose_w(const float* __restrict__ W,
                                                   __hip_bfloat16* __restrict__ Wt,
                                                   int K, int N) {
    int i = blockIdx.x * 256 + threadIdx.x;
    if (i >= K * N) return;
    int k = i / N, n = i - k * N;
    Wt[(size_t)n * K + k] = __float2bfloat16(W[i]);
}

// --------- bf16 MFMA GEMM: C[M,NC](bf16) = A[M,K](bf16) @ Bt[NC,K]^T ---------
// 128x128 tile, BK=32, 256 threads (4 waves, 2x2), double-buffered LDS via
// global_load_lds width=16, XOR swizzle (slot ^= (row>>1)&3) on both sides.
template <int K>
__global__ __launch_bounds__(256) void gemm_mfma(
        const __hip_bfloat16* __restrict__ A,
        const __hip_bfloat16* __restrict__ Bt,
        __hip_bfloat16* __restrict__ C,
        int M, int NC) {
    constexpr int KS = K / 32;
    __shared__ __hip_bfloat16 Alds[2][128][32];
    __shared__ __hip_bfloat16 Blds[2][128][32];
    const int tid  = threadIdx.x;
    const int w    = tid >> 6;
    const int lane = tid & 63;
    const int wr   = w >> 1, wc = w & 1;
    const int bm = blockIdx.y * 128, bn = blockIdx.x * 128;

    auto stage = [&](int t, int b) {
        const int k0 = t * 32;
#pragma unroll
        for (int i = 0; i < 2; ++i) {
            int ld    = (w << 1) | i;          // 0..7
            int rrel0 = ld << 4;               // 16-row group
            int rrel  = rrel0 + (lane >> 2);
            int slot  = lane & 3;
            int cg    = ((slot ^ ((rrel >> 1) & 3)) << 3);  // pre-swizzled col grp
            int arow  = bm + rrel; arow = arow < M ? arow : M - 1;
            GLOAD_LDS16(A  + (size_t)arow * K + k0 + cg, &Alds[b][rrel0][0]);
            int brow  = bn + rrel;             // NC multiple of 128 -> in range
            GLOAD_LDS16(Bt + (size_t)brow * K + k0 + cg, &Blds[b][rrel0][0]);
        }
    };

    f32x4 acc[4][4] = {};
    stage(0, 0);
    __syncthreads();                           // drains vmcnt before reads

    const int fr = lane & 15, fq = lane >> 4;
    for (int t = 0; t < KS; ++t) {
        const int b = t & 1;
        if (t + 1 < KS) stage(t + 1, b ^ 1);
        frag af[4], bf[4];
#pragma unroll
        for (int mf = 0; mf < 4; ++mf) {
            int arel = (wr << 6) + (mf << 4) + fr;
            int p = fq ^ ((arel >> 1) & 3);
            af[mf] = *(const frag*)&Alds[b][arel][p << 3];
        }
#pragma unroll
        for (int nf = 0; nf < 4; ++nf) {
            int nrel = (wc << 6) + (nf << 4) + fr;
            int p = fq ^ ((nrel >> 1) & 3);
            bf[nf] = *(const frag*)&Blds[b][nrel][p << 3];
        }
#pragma unroll
        for (int mf = 0; mf < 4; ++mf)
#pragma unroll
            for (int nf = 0; nf < 4; ++nf)
                acc[mf][nf] = __builtin_amdgcn_mfma_f32_16x16x32_bf16(
                    af[mf], bf[nf], acc[mf][nf], 0, 0, 0);
        __syncthreads();                       // also drains next-stage vmcnt
    }

    // C/D layout: col = lane&15, row = (lane>>4)*4 + reg   [m89-verified]
#pragma unroll
    for (int mf = 0; mf < 4; ++mf)
#pragma unroll
        for (int r = 0; r < 4; ++r) {
            int row = bm + (wr << 6) + (mf << 4) + (fq << 2) + r;
            if (row < M) {
#pragma unroll
                for (int nf = 0; nf < 4; ++nf) {
                    int col = bn + (wc << 6) + (nf << 4) + fr;
                    C[(size_t)row * NC + col] = __float2bfloat16(acc[mf][nf][r]);
                }
            }
        }
}

// ---------------- CSR build ----------------
__global__ void count_deg(const int* __restrict__ ei, int E, int Etot,
                          int* __restrict__ deg) {
    int e = blockIdx.x * blockDim.x + threadIdx.x;
    if (e >= Etot) return;
    int d = (e < E) ? ei[E + e] : (e - E);   // self-loop for e >= E
    atomicAdd(&deg[d], 1);
}

__global__ __launch_bounds__(1024) void scan_excl(const int* __restrict__ deg,
                                                  int* __restrict__ rowptr, int n) {
    __shared__ int buf[1024];
    int t = threadIdx.x;
    int carry = 0;
    for (int base = 0; base < n; base += 1024) {
        int i = base + t;
        int v = (i < n) ? deg[i] : 0;
        buf[t] = v;
        __syncthreads();
#pragma unroll
        for (int off = 1; off < 1024; off <<= 1) {
            int xv = (t >= off) ? buf[t - off] : 0;
            __syncthreads();
            buf[t] += xv;
            __syncthreads();
        }
        if (i < n) rowptr[i] = carry + buf[t] - v;
        carry += buf[1023];
        __syncthreads();
    }
    if (t == 0) rowptr[n] = carry;
}

__global__ void fill_csr(const int* __restrict__ ei, int E, int Etot,
                         const int* __restrict__ rowptr, int* __restrict__ cursor,
                         int* __restrict__ csrc) {
    int e = blockIdx.x * blockDim.x + threadIdx.x;
    if (e >= Etot) return;
    int s, d;
    if (e < E) { s = ei[e]; d = ei[E + e]; }
    else       { s = e - E; d = s; }
    int pos = rowptr[d] + atomicAdd(&cursor[d], 1);
    csrc[pos] = s;
}

// -------- bf16 row fragment -> fp32 registers --------
template <int CPL>
__device__ __forceinline__ void bload(float* d, const __hip_bfloat16* p) {
    if constexpr (CPL == 4) {
        uint2 u = *(const uint2*)p;
        d[0] = __uint_as_float(u.x << 16);
        d[1] = __uint_as_float(u.x & 0xffff0000u);
        d[2] = __uint_as_float(u.y << 16);
        d[3] = __uint_as_float(u.y & 0xffff0000u);
    } else {
        unsigned u = *(const unsigned*)p;
        d[0] = __uint_as_float(u << 16);
        d[1] = __uint_as_float(u & 0xffff0000u);
    }
}

// ---- fused GATv2 attention + aggregate: one wave per node, online softmax ----
template <int C, int H>
__global__ __launch_bounds__(256) void gat_agg(
        const __hip_bfloat16* __restrict__ XL,
        const __hip_bfloat16* __restrict__ XR,
        const int* __restrict__ rowptr, const int* __restrict__ csrc,
        const float* __restrict__ att, const float* __restrict__ bias,
        float* __restrict__ OUT, int N) {
    constexpr int CPL = C / 64;
    constexpr int LPH = 64 / H;     // lanes per head
    int node = (blockIdx.x * blockDim.x + threadIdx.x) >> 6;
    int lane = threadIdx.x & 63;
    if (node >= N) return;
    int ch0 = lane * CPL;

    float attv[CPL], xrv[CPL];
    bload<CPL>(xrv, XR + (size_t)node * C + ch0);
#pragma unroll
    for (int j = 0; j < CPL; ++j) attv[j] = att[ch0 + j];

    float m = -INFINITY, sumw = 0.f;
    float acc[CPL];
#pragma unroll
    for (int j = 0; j < CPL; ++j) acc[j] = 0.f;

    const int e0 = rowptr[node], e1 = rowptr[node + 1];  // deg >= 1 (self-loop)
    float nxt[CPL];
    bload<CPL>(nxt, XL + (size_t)csrc[e0] * C + ch0);
    for (int k = e0; k < e1; ++k) {
        float xlv[CPL];
#pragma unroll
        for (int j = 0; j < CPL; ++j) xlv[j] = nxt[j];
        if (k + 1 < e1)                                   // prefetch next src row
            bload<CPL>(nxt, XL + (size_t)csrc[k + 1] * C + ch0);

        float partial = 0.f;
#pragma unroll
        for (int j = 0; j < CPL; ++j) {
            float v = xlv[j] + xrv[j];
            v = v > 0.f ? v : NEG_SLOPE * v;
            partial = fmaf(v, attv[j], partial);
        }
#pragma unroll
        for (int off = 1; off < LPH; off <<= 1)
            partial += __shfl_xor(partial, off, 64);
        float l = partial;                                // head logit

        // branchless online-softmax update
        float mn = fmaxf(m, l);
        float wl = __expf(l - mn);
        float rm = __expf(m - mn);
        sumw = fmaf(sumw, rm, wl);
#pragma unroll
        for (int j = 0; j < CPL; ++j)
            acc[j] = fmaf(acc[j], rm, wl * xlv[j]);
        m = mn;
    }
    float inv = 1.f / sumw;
#pragma unroll
    for (int j = 0; j < CPL; ++j)
        OUT[(size_t)node * C + ch0 + j] = fmaf(acc[j], inv, bias[ch0 + j]);
}

// ---------------- batchnorm ----------------
__global__ __launch_bounds__(256) void bn_stats(const float* __restrict__ Hm,
        float* __restrict__ sums, float* __restrict__ sqs, int N, int C) {
    int ch = threadIdx.x;               // C == 256 == blockDim.x
    int r0 = blockIdx.x * 256;
    int r1 = min(N, r0 + 256);
    float s = 0.f, q = 0.f;
    for (int r = r0; r < r1; ++r) {
        float v = Hm[(size_t)r * C + ch];
        s += v;
        q = fmaf(v, v, q);
    }
    atomicAdd(&sums[ch], s);
    atomicAdd(&sqs[ch], q);
}

// reads fp32 pre-BN, writes bf16 activation (feeds next layer's GEMM)
__global__ __launch_bounds__(256) void bn_elu(const float* __restrict__ Hm,
        __hip_bfloat16* __restrict__ Ob,
        const float* __restrict__ sums, const float* __restrict__ sqs,
        const float* __restrict__ gamma, const float* __restrict__ beta,
        int total, int C, float invN) {
    int idx = blockIdx.x * 256 + threadIdx.x;
    if (idx >= total) return;
    int ch = idx & (C - 1);
    float mu = sums[ch] * invN;
    float var = sqs[ch] * invN - mu * mu;
    float sc = gamma[ch] * rsqrtf(var + BN_EPS);
    float v = (Hm[idx] - mu) * sc + beta[ch];
    v = v > 0.f ? v : expm1f(v);
    Ob[idx] = __float2bfloat16(v);
}

extern "C" void kernel_launch(void* const* d_in, const int* in_sizes, int n_in,
                              void* d_out, int out_size, void* d_ws, size_t ws_size,
                              hipStream_t stream) {
    const float* x    = (const float*)d_in[0];
    const int*   ei   = (const int*)d_in[1];
    const float* Wl1  = (const float*)d_in[2];
    const float* Wr1  = (const float*)d_in[3];
    const float* att1 = (const float*)d_in[4];
    const float* b1   = (const float*)d_in[5];
    const float* g1   = (const float*)d_in[6];
    const float* be1  = (const float*)d_in[7];
    const float* Wl2  = (const float*)d_in[8];
    const float* Wr2  = (const float*)d_in[9];
    const float* att2 = (const float*)d_in[10];
    const float* b2   = (const float*)d_in[11];
    const float* g2   = (const float*)d_in[12];
    const float* be2  = (const float*)d_in[13];
    const float* Wl3  = (const float*)d_in[14];
    const float* Wr3  = (const float*)d_in[15];
    const float* att3 = (const float*)d_in[16];
    const float* b3   = (const float*)d_in[17];
    float* out = (float*)d_out;

    const int IN_F = 128, HC = 256, OUT_F = 128;
    const int N = in_sizes[0] / IN_F;     // 50000
    const int E = in_sizes[1] / 2;        // 800000
    const int Etot = E + N;               // 850000

    // ---- workspace carve-up (all offsets 256B aligned) ----
    char* p = (char*)d_ws;
    auto alloc = [&](size_t bytes) {
        void* r = (void*)p;
        p += (bytes + 255) & ~(size_t)255;
        return r;
    };
    __hip_bfloat16* XL   = (__hip_bfloat16*)alloc((size_t)N * HC * 2);
    __hip_bfloat16* XR   = (__hip_bfloat16*)alloc((size_t)N * HC * 2);
    float* Hb            = (float*)alloc((size_t)N * HC * 4);
    __hip_bfloat16* Hbb  = (__hip_bfloat16*)alloc((size_t)N * HC * 2);
    __hip_bfloat16* xbf  = (__hip_bfloat16*)alloc((size_t)N * IN_F * 2);
    __hip_bfloat16* W1lt = (__hip_bfloat16*)alloc((size_t)IN_F * HC * 2);
    __hip_bfloat16* W1rt = (__hip_bfloat16*)alloc((size_t)IN_F * HC * 2);
    __hip_bfloat16* W2lt = (__hip_bfloat16*)alloc((size_t)HC * HC * 2);
    __hip_bfloat16* W2rt = (__hip_bfloat16*)alloc((size_t)HC * HC * 2);
    __hip_bfloat16* W3lt = (__hip_bfloat16*)alloc((size_t)HC * OUT_F * 2);
    __hip_bfloat16* W3rt = (__hip_bfloat16*)alloc((size_t)HC * OUT_F * 2);
    int* deg       = (int*)alloc((size_t)N * 4);
    int* rowptr    = (int*)alloc((size_t)(N + 1) * 4);
    int* cursor    = (int*)alloc((size_t)N * 4);
    int* csrc      = (int*)alloc((size_t)Etot * 4);
    float* bns     = (float*)alloc((size_t)HC * 4);
    float* bnq     = (float*)alloc((size_t)HC * 4);

    const int eb = (Etot + 255) / 256;
    const int nb = (N + 3) / 4;
    const int gemmRows = (N + 127) / 128;

    // ---- one-time conversions ----
    f32_to_bf16<<<(N * IN_F / 4 + 255) / 256, 256, 0, stream>>>(x, xbf, N * IN_F / 4);
    transpose_w<<<(IN_F * HC + 255) / 256, 256, 0, stream>>>(Wl1, W1lt, IN_F, HC);
    transpose_w<<<(IN_F * HC + 255) / 256, 256, 0, stream>>>(Wr1, W1rt, IN_F, HC);
    transpose_w<<<(HC * HC + 255) / 256, 256, 0, stream>>>(Wl2, W2lt, HC, HC);
    transpose_w<<<(HC * HC + 255) / 256, 256, 0, stream>>>(Wr2, W2rt, HC, HC);
    transpose_w<<<(HC * OUT_F + 255) / 256, 256, 0, stream>>>(Wl3, W3lt, HC, OUT_F);
    transpose_w<<<(HC * OUT_F + 255) / 256, 256, 0, stream>>>(Wr3, W3rt, HC, OUT_F);

    // ---- CSR by dst (built once, reused by all 3 layers) ----
    hipMemsetAsync(deg, 0, (size_t)N * 4, stream);
    count_deg<<<eb, 256, 0, stream>>>(ei, E, Etot, deg);
    scan_excl<<<1, 1024, 0, stream>>>(deg, rowptr, N);
    hipMemsetAsync(cursor, 0, (size_t)N * 4, stream);
    fill_csr<<<eb, 256, 0, stream>>>(ei, E, Etot, rowptr, cursor, csrc);

    // ================= Layer 1 (K=128) =================
    gemm_mfma<128><<<dim3(HC / 128, gemmRows), 256, 0, stream>>>(xbf, W1lt, XL, N, HC);
    gemm_mfma<128><<<dim3(HC / 128, gemmRows), 256, 0, stream>>>(xbf, W1rt, XR, N, HC);
    gat_agg<256, 4><<<nb, 256, 0, stream>>>(XL, XR, rowptr, csrc, att1, b1, Hb, N);
    hipMemsetAsync(bns, 0, HC * 4, stream);
    hipMemsetAsync(bnq, 0, HC * 4, stream);
    bn_stats<<<(N + 255) / 256, 256, 0, stream>>>(Hb, bns, bnq, N, HC);
    bn_elu<<<(N * HC + 255) / 256, 256, 0, stream>>>(Hb, Hbb, bns, bnq, g1, be1, N * HC, HC, 1.f / N);

    // ================= Layer 2 (K=256) =================
    gemm_mfma<256><<<dim3(HC / 128, gemmRows), 256, 0, stream>>>(Hbb, W2lt, XL, N, HC);
    gemm_mfma<256><<<dim3(HC / 128, gemmRows), 256, 0, stream>>>(Hbb, W2rt, XR, N, HC);
    gat_agg<256, 4><<<nb, 256, 0, stream>>>(XL, XR, rowptr, csrc, att2, b2, Hb, N);
    hipMemsetAsync(bns, 0, HC * 4, stream);
    hipMemsetAsync(bnq, 0, HC * 4, stream);
    bn_stats<<<(N + 255) / 256, 256, 0, stream>>>(Hb, bns, bnq, N, HC);
    bn_elu<<<(N * HC + 255) / 256, 256, 0, stream>>>(Hb, Hbb, bns, bnq, g2, be2, N * HC, HC, 1.f / N);

    // ================= Layer 3 (K=256, 1 head, 128 ch, mean==identity) ======
    gemm_mfma<256><<<dim3(OUT_F / 128, gemmRows), 256, 0, stream>>>(Hbb, W3lt, XL, N, OUT_F);
    gemm_mfma<256><<<dim3(OUT_F / 128, gemmRows), 256, 0, stream>>>(Hbb, W3rt, XR, N, OUT_F);
    gat_agg<128, 1><<<nb, 256, 0, stream>>>(XL, XR, rowptr, csrc, att3, b3, out, N);
}

// Round 4
// 700.381 us; speedup vs baseline: 2.5102x; 1.1338x over previous
//
#include <hip/hip_runtime.h>
#include <hip/hip_bf16.h>
#include <math.h>

#define NEG_SLOPE 0.2f
#define BN_EPS 1e-5f

using frag  = __attribute__((ext_vector_type(8))) short;   // 8 x bf16
using f32x4 = __attribute__((ext_vector_type(4))) float;

#define GLOAD_LDS16(gp, lp) __builtin_amdgcn_global_load_lds( \
    (const __attribute__((address_space(1))) void*)(gp),      \
    (__attribute__((address_space(3))) void*)(lp), 16, 0, 0)

// ---------------- conversions ----------------
__global__ __launch_bounds__(256) void f32_to_bf16(const float* __restrict__ in,
                                                   __hip_bfloat16* __restrict__ out,
                                                   int n4) {   // n4 = n/4
    int i = blockIdx.x * 256 + threadIdx.x;
    if (i >= n4) return;
    float4 v = *(const float4*)(in + (size_t)i * 4);
    __hip_bfloat16 h[4] = {__float2bfloat16(v.x), __float2bfloat16(v.y),
                           __float2bfloat16(v.z), __float2bfloat16(v.w)};
    *(uint2*)(out + (size_t)i * 4) = *(const uint2*)h;
}

// W[K][N] fp32 -> Wt[N][K] bf16
__global__ __launch_bounds__(256) void transpose_w(const float* __restrict__ W,
                                                   __hip_bfloat16* __restrict__ Wt,
                                                   int K, int N) {
    int i = blockIdx.x * 256 + threadIdx.x;
    if (i >= K * N) return;
    int k = i / N, n = i - k * N;
    Wt[(size_t)n * K + k] = __float2bfloat16(W[i]);
}

// --------- bf16 MFMA GEMM: C[M,NC](bf16) = A[M,K](bf16) @ Bt[NC,K]^T ---------
// 128x128 tile, BK=32, 256 threads (4 waves, 2x2), double-buffered LDS via
// global_load_lds width=16, XOR swizzle (slot ^= (row>>1)&3) on both sides.
template <int K>
__global__ __launch_bounds__(256) void gemm_mfma(
        const __hip_bfloat16* __restrict__ A,
        const __hip_bfloat16* __restrict__ Bt,
        __hip_bfloat16* __restrict__ C,
        int M, int NC) {
    constexpr int KS = K / 32;
    __shared__ __hip_bfloat16 Alds[2][128][32];
    __shared__ __hip_bfloat16 Blds[2][128][32];
    const int tid  = threadIdx.x;
    const int w    = tid >> 6;
    const int lane = tid & 63;
    const int wr   = w >> 1, wc = w & 1;
    const int bm = blockIdx.y * 128, bn = blockIdx.x * 128;

    auto stage = [&](int t, int b) {
        const int k0 = t * 32;
#pragma unroll
        for (int i = 0; i < 2; ++i) {
            int ld    = (w << 1) | i;          // 0..7
            int rrel0 = ld << 4;               // 16-row group
            int rrel  = rrel0 + (lane >> 2);
            int slot  = lane & 3;
            int cg    = ((slot ^ ((rrel >> 1) & 3)) << 3);  // pre-swizzled col grp
            int arow  = bm + rrel; arow = arow < M ? arow : M - 1;
            GLOAD_LDS16(A  + (size_t)arow * K + k0 + cg, &Alds[b][rrel0][0]);
            int brow  = bn + rrel;             // NC multiple of 128 -> in range
            GLOAD_LDS16(Bt + (size_t)brow * K + k0 + cg, &Blds[b][rrel0][0]);
        }
    };

    f32x4 acc[4][4] = {};
    stage(0, 0);
    __syncthreads();                           // drains vmcnt before reads

    const int fr = lane & 15, fq = lane >> 4;
    for (int t = 0; t < KS; ++t) {
        const int b = t & 1;
        if (t + 1 < KS) stage(t + 1, b ^ 1);
        frag af[4], bf[4];
#pragma unroll
        for (int mf = 0; mf < 4; ++mf) {
            int arel = (wr << 6) + (mf << 4) + fr;
            int p = fq ^ ((arel >> 1) & 3);
            af[mf] = *(const frag*)&Alds[b][arel][p << 3];
        }
#pragma unroll
        for (int nf = 0; nf < 4; ++nf) {
            int nrel = (wc << 6) + (nf << 4) + fr;
            int p = fq ^ ((nrel >> 1) & 3);
            bf[nf] = *(const frag*)&Blds[b][nrel][p << 3];
        }
#pragma unroll
        for (int mf = 0; mf < 4; ++mf)
#pragma unroll
            for (int nf = 0; nf < 4; ++nf)
                acc[mf][nf] = __builtin_amdgcn_mfma_f32_16x16x32_bf16(
                    af[mf], bf[nf], acc[mf][nf], 0, 0, 0);
        __syncthreads();                       // also drains next-stage vmcnt
    }

    // C/D layout: col = lane&15, row = (lane>>4)*4 + reg   [m89-verified]
#pragma unroll
    for (int mf = 0; mf < 4; ++mf)
#pragma unroll
        for (int r = 0; r < 4; ++r) {
            int row = bm + (wr << 6) + (mf << 4) + (fq << 2) + r;
            if (row < M) {
#pragma unroll
                for (int nf = 0; nf < 4; ++nf) {
                    int col = bn + (wc << 6) + (nf << 4) + fr;
                    C[(size_t)row * NC + col] = __float2bfloat16(acc[mf][nf][r]);
                }
            }
        }
}

// ---------------- CSR build ----------------
__global__ void count_deg(const int* __restrict__ ei, int E, int Etot,
                          int* __restrict__ deg) {
    int e = blockIdx.x * blockDim.x + threadIdx.x;
    if (e >= Etot) return;
    int d = (e < E) ? ei[E + e] : (e - E);   // self-loop for e >= E
    atomicAdd(&deg[d], 1);
}

// three-phase exclusive scan: per-block scan, wave-scan of partials, add-back
__global__ __launch_bounds__(1024) void scan1(const int* __restrict__ deg,
                                              int* __restrict__ pre,
                                              int* __restrict__ bsum, int n) {
    __shared__ int buf[1024];
    int t = threadIdx.x;
    int i = blockIdx.x * 1024 + t;
    int v = (i < n) ? deg[i] : 0;
    buf[t] = v;
    __syncthreads();
#pragma unroll
    for (int off = 1; off < 1024; off <<= 1) {
        int xv = (t >= off) ? buf[t - off] : 0;
        __syncthreads();
        buf[t] += xv;
        __syncthreads();
    }
    if (i < n) pre[i] = buf[t] - v;          // exclusive within block
    if (t == 1023) bsum[blockIdx.x] = buf[1023];
}

__global__ void scan2(int* __restrict__ bsum, int nb) {   // nb <= 64, 1 wave
    int t = threadIdx.x;
    int v = (t < nb) ? bsum[t] : 0;
    int s = v;
#pragma unroll
    for (int off = 1; off < 64; off <<= 1) {
        int u = __shfl_up(s, off, 64);
        if (t >= off) s += u;
    }
    if (t < nb) bsum[t] = s - v;             // exclusive
}

__global__ __launch_bounds__(256) void scan3(const int* __restrict__ pre,
                                             const int* __restrict__ bsum,
                                             int* __restrict__ rowptr,
                                             int n, int Etot) {
    int i = blockIdx.x * 256 + threadIdx.x;
    if (i < n) rowptr[i] = pre[i] + bsum[i >> 10];
    if (i == 0) rowptr[n] = Etot;
}

__global__ void fill_csr(const int* __restrict__ ei, int E, int Etot,
                         const int* __restrict__ rowptr, int* __restrict__ cursor,
                         int* __restrict__ csrc) {
    int e = blockIdx.x * blockDim.x + threadIdx.x;
    if (e >= Etot) return;
    int s, d;
    if (e < E) { s = ei[e]; d = ei[E + e]; }
    else       { s = e - E; d = s; }
    int pos = rowptr[d] + atomicAdd(&cursor[d], 1);
    csrc[pos] = s;
}

// -------- bf16 row fragment -> fp32 registers --------
template <int CPL>
__device__ __forceinline__ void bload(float* d, const __hip_bfloat16* p) {
    if constexpr (CPL == 4) {
        uint2 u = *(const uint2*)p;
        d[0] = __uint_as_float(u.x << 16);
        d[1] = __uint_as_float(u.x & 0xffff0000u);
        d[2] = __uint_as_float(u.y << 16);
        d[3] = __uint_as_float(u.y & 0xffff0000u);
    } else {
        unsigned u = *(const unsigned*)p;
        d[0] = __uint_as_float(u << 16);
        d[1] = __uint_as_float(u & 0xffff0000u);
    }
}

template <int CPL, typename OutT>
__device__ __forceinline__ void store_out(OutT* p, const float* v) {
    if constexpr (sizeof(OutT) == 2) {
        __hip_bfloat16 h[CPL];
#pragma unroll
        for (int j = 0; j < CPL; ++j) h[j] = __float2bfloat16(v[j]);
        if constexpr (CPL == 4) *(uint2*)p = *(const uint2*)h;
        else                    *(unsigned*)p = *(const unsigned*)h;
    } else {
        if constexpr (CPL == 4) *(float4*)p = *(const float4*)v;
        else                    *(float2*)p = *(const float2*)v;
    }
}

// ---- fused GATv2 attention + aggregate: one wave per node, defer-max softmax.
// XLR[N][S]: XL = cols 0..C-1, XR = cols C..2C-1.
template <int C, int H, int S, typename OutT>
__global__ __launch_bounds__(256) void gat_agg(
        const __hip_bfloat16* __restrict__ XLR,
        const int* __restrict__ rowptr, const int* __restrict__ csrc,
        const float* __restrict__ att, const float* __restrict__ bias,
        OutT* __restrict__ OUT, int N) {
    constexpr int CPL = C / 64;
    constexpr int LPH = 64 / H;     // lanes per head
    int node = (blockIdx.x * blockDim.x + threadIdx.x) >> 6;
    int lane = threadIdx.x & 63;
    if (node >= N) return;
    int ch0 = lane * CPL;

    float attv[CPL], attv5[CPL], xrv[CPL];
    bload<CPL>(xrv, XLR + (size_t)node * S + C + ch0);
#pragma unroll
    for (int j = 0; j < CPL; ++j) {
        attv[j]  = att[ch0 + j];
        attv5[j] = attv[j] * NEG_SLOPE;
    }

    float m = -INFINITY, sumw = 0.f;
    float acc[CPL];
#pragma unroll
    for (int j = 0; j < CPL; ++j) acc[j] = 0.f;

    const int e0 = rowptr[node], e1 = rowptr[node + 1];  // deg >= 1 (self-loop)
    float nxt[CPL];
    bload<CPL>(nxt, XLR + (size_t)csrc[e0] * S + ch0);
    for (int k = e0; k < e1; ++k) {
        float xlv[CPL];
#pragma unroll
        for (int j = 0; j < CPL; ++j) xlv[j] = nxt[j];
        if (k + 1 < e1)                                   // prefetch next src row
            bload<CPL>(nxt, XLR + (size_t)csrc[k + 1] * S + ch0);

        float partial = 0.f;
#pragma unroll
        for (int j = 0; j < CPL; ++j) {
            float v = xlv[j] + xrv[j];
            partial = fmaf(v, v > 0.f ? attv[j] : attv5[j], partial);
        }
#pragma unroll
        for (int off = 1; off < LPH; off <<= 1)
            partial += __shfl_xor(partial, off, 64);
        float l = partial;                                // head logit

        // defer-max: rescale only when base grows by > 8 (first edge: m=-inf,
        // exp(-inf)=0 zeroes history for free)
        if (l > m + 8.f) {
            float rs = __expf(m - l);
            sumw *= rs;
#pragma unroll
            for (int j = 0; j < CPL; ++j) acc[j] *= rs;
            m = l;
        }
        float w = __expf(l - m);
        sumw += w;
#pragma unroll
        for (int j = 0; j < CPL; ++j)
            acc[j] = fmaf(w, xlv[j], acc[j]);
    }
    float inv = 1.f / sumw;
    float o[CPL];
#pragma unroll
    for (int j = 0; j < CPL; ++j)
        o[j] = fmaf(acc[j], inv, bias[ch0 + j]);
    store_out<CPL>(OUT + (size_t)node * C + ch0, o);
}

// ---------------- batchnorm (bf16 I/O, fp32 math) ----------------
__global__ __launch_bounds__(256) void bn_stats(const __hip_bfloat16* __restrict__ Hm,
        float* __restrict__ sums, float* __restrict__ sqs, int N, int C) {
    int ch = threadIdx.x;               // C == 256 == blockDim.x
    int r0 = blockIdx.x * 256;
    int r1 = min(N, r0 + 256);
    float s = 0.f, q = 0.f;
    for (int r = r0; r < r1; ++r) {
        float v = __bfloat162float(Hm[(size_t)r * C + ch]);
        s += v;
        q = fmaf(v, v, q);
    }
    atomicAdd(&sums[ch], s);
    atomicAdd(&sqs[ch], q);
}

__global__ __launch_bounds__(256) void bn_elu(const __hip_bfloat16* __restrict__ Hm,
        __hip_bfloat16* __restrict__ Ob,
        const float* __restrict__ sums, const float* __restrict__ sqs,
        const float* __restrict__ gamma, const float* __restrict__ beta,
        int total, int C, float invN) {
    int idx = blockIdx.x * 256 + threadIdx.x;
    if (idx >= total) return;
    int ch = idx & (C - 1);
    float mu = sums[ch] * invN;
    float var = sqs[ch] * invN - mu * mu;
    float sc = gamma[ch] * rsqrtf(var + BN_EPS);
    float v = (__bfloat162float(Hm[idx]) - mu) * sc + beta[ch];
    v = v > 0.f ? v : expm1f(v);
    Ob[idx] = __float2bfloat16(v);
}

extern "C" void kernel_launch(void* const* d_in, const int* in_sizes, int n_in,
                              void* d_out, int out_size, void* d_ws, size_t ws_size,
                              hipStream_t stream) {
    const float* x    = (const float*)d_in[0];
    const int*   ei   = (const int*)d_in[1];
    const float* Wl1  = (const float*)d_in[2];
    const float* Wr1  = (const float*)d_in[3];
    const float* att1 = (const float*)d_in[4];
    const float* b1   = (const float*)d_in[5];
    const float* g1   = (const float*)d_in[6];
    const float* be1  = (const float*)d_in[7];
    const float* Wl2  = (const float*)d_in[8];
    const float* Wr2  = (const float*)d_in[9];
    const float* att2 = (const float*)d_in[10];
    const float* b2   = (const float*)d_in[11];
    const float* g2   = (const float*)d_in[12];
    const float* be2  = (const float*)d_in[13];
    const float* Wl3  = (const float*)d_in[14];
    const float* Wr3  = (const float*)d_in[15];
    const float* att3 = (const float*)d_in[16];
    const float* b3   = (const float*)d_in[17];
    float* out = (float*)d_out;

    const int IN_F = 128, HC = 256, OUT_F = 128;
    const int N = in_sizes[0] / IN_F;     // 50000
    const int E = in_sizes[1] / 2;        // 800000
    const int Etot = E + N;               // 850000

    // ---- workspace carve-up ----
    char* p = (char*)d_ws;
    auto alloc = [&](size_t bytes) {
        void* r = (void*)p;
        p += (bytes + 255) & ~(size_t)255;
        return r;
    };
    __hip_bfloat16* XLR  = (__hip_bfloat16*)alloc((size_t)N * 2 * HC * 2);  // [N][512]
    __hip_bfloat16* Hb   = (__hip_bfloat16*)alloc((size_t)N * HC * 2);
    __hip_bfloat16* Hbb  = (__hip_bfloat16*)alloc((size_t)N * HC * 2);
    __hip_bfloat16* xbf  = (__hip_bfloat16*)alloc((size_t)N * IN_F * 2);
    __hip_bfloat16* Wc1  = (__hip_bfloat16*)alloc((size_t)2 * HC * IN_F * 2);   // [512][128]
    __hip_bfloat16* Wc2  = (__hip_bfloat16*)alloc((size_t)2 * HC * HC * 2);     // [512][256]
    __hip_bfloat16* Wc3  = (__hip_bfloat16*)alloc((size_t)2 * OUT_F * HC * 2);  // [256][256]
    int* deg       = (int*)alloc((size_t)N * 4);
    int* pre       = (int*)alloc((size_t)N * 4);
    int* bsum      = (int*)alloc(64 * 4);
    int* rowptr    = (int*)alloc((size_t)(N + 1) * 4);
    int* cursor    = (int*)alloc((size_t)N * 4);
    int* csrc      = (int*)alloc((size_t)Etot * 4);
    float* bns     = (float*)alloc((size_t)HC * 4);
    float* bnq     = (float*)alloc((size_t)HC * 4);

    const int eb = (Etot + 255) / 256;
    const int nb = (N + 3) / 4;
    const int gemmRows = (N + 127) / 128;
    const int scanB = (N + 1023) / 1024;

    // ---- one-time conversions (weights concatenated [Wl; Wr] transposed) ----
    f32_to_bf16<<<(N * IN_F / 4 + 255) / 256, 256, 0, stream>>>(x, xbf, N * IN_F / 4);
    transpose_w<<<(IN_F * HC + 255) / 256, 256, 0, stream>>>(Wl1, Wc1, IN_F, HC);
    transpose_w<<<(IN_F * HC + 255) / 256, 256, 0, stream>>>(Wr1, Wc1 + (size_t)HC * IN_F, IN_F, HC);
    transpose_w<<<(HC * HC + 255) / 256, 256, 0, stream>>>(Wl2, Wc2, HC, HC);
    transpose_w<<<(HC * HC + 255) / 256, 256, 0, stream>>>(Wr2, Wc2 + (size_t)HC * HC, HC, HC);
    transpose_w<<<(HC * OUT_F + 255) / 256, 256, 0, stream>>>(Wl3, Wc3, HC, OUT_F);
    transpose_w<<<(HC * OUT_F + 255) / 256, 256, 0, stream>>>(Wr3, Wc3 + (size_t)OUT_F * HC, HC, OUT_F);

    // ---- CSR by dst (built once, reused by all 3 layers) ----
    hipMemsetAsync(deg, 0, (size_t)N * 4, stream);
    count_deg<<<eb, 256, 0, stream>>>(ei, E, Etot, deg);
    scan1<<<scanB, 1024, 0, stream>>>(deg, pre, bsum, N);
    scan2<<<1, 64, 0, stream>>>(bsum, scanB);
    scan3<<<(N + 255) / 256, 256, 0, stream>>>(pre, bsum, rowptr, N, Etot);
    hipMemsetAsync(cursor, 0, (size_t)N * 4, stream);
    fill_csr<<<eb, 256, 0, stream>>>(ei, E, Etot, rowptr, cursor, csrc);

    // ================= Layer 1 (K=128): one GEMM -> XLR[N][512] =============
    gemm_mfma<128><<<dim3(4, gemmRows), 256, 0, stream>>>(xbf, Wc1, XLR, N, 2 * HC);
    gat_agg<256, 4, 512><<<nb, 256, 0, stream>>>(XLR, rowptr, csrc, att1, b1, Hb, N);
    hipMemsetAsync(bns, 0, HC * 4, stream);
    hipMemsetAsync(bnq, 0, HC * 4, stream);
    bn_stats<<<(N + 255) / 256, 256, 0, stream>>>(Hb, bns, bnq, N, HC);
    bn_elu<<<(N * HC + 255) / 256, 256, 0, stream>>>(Hb, Hbb, bns, bnq, g1, be1, N * HC, HC, 1.f / N);

    // ================= Layer 2 (K=256) ======================================
    gemm_mfma<256><<<dim3(4, gemmRows), 256, 0, stream>>>(Hbb, Wc2, XLR, N, 2 * HC);
    gat_agg<256, 4, 512><<<nb, 256, 0, stream>>>(XLR, rowptr, csrc, att2, b2, Hb, N);
    hipMemsetAsync(bns, 0, HC * 4, stream);
    hipMemsetAsync(bnq, 0, HC * 4, stream);
    bn_stats<<<(N + 255) / 256, 256, 0, stream>>>(Hb, bns, bnq, N, HC);
    bn_elu<<<(N * HC + 255) / 256, 256, 0, stream>>>(Hb, Hbb, bns, bnq, g2, be2, N * HC, HC, 1.f / N);

    // ================= Layer 3 (K=256, 1 head, 128 ch) ======================
    gemm_mfma<256><<<dim3(2, gemmRows), 256, 0, stream>>>(Hbb, Wc3, XLR, N, 2 * OUT_F);
    gat_agg<128, 1, 256><<<nb, 256, 0, stream>>>(XLR, rowptr, csrc, att3, b3, out, N);
}

// Round 5
// 590.623 us; speedup vs baseline: 2.9767x; 1.1858x over previous
//
#include <hip/hip_runtime.h>
#include <hip/hip_bf16.h>
#include <math.h>

#define NEG_SLOPE 0.2f
#define BN_EPS 1e-5f

using frag  = __attribute__((ext_vector_type(8))) short;   // 8 x bf16
using f32x4 = __attribute__((ext_vector_type(4))) float;

#define GLOAD_LDS16(gp, lp) __builtin_amdgcn_global_load_lds( \
    (const __attribute__((address_space(1))) void*)(gp),      \
    (__attribute__((address_space(3))) void*)(lp), 16, 0, 0)

// ---------------- conversions ----------------
__global__ __launch_bounds__(256) void f32_to_bf16(const float* __restrict__ in,
                                                   __hip_bfloat16* __restrict__ out,
                                                   int n4) {   // n4 = n/4
    int i = blockIdx.x * 256 + threadIdx.x;
    if (i >= n4) return;
    float4 v = *(const float4*)(in + (size_t)i * 4);
    __hip_bfloat16 h[4] = {__float2bfloat16(v.x), __float2bfloat16(v.y),
                           __float2bfloat16(v.z), __float2bfloat16(v.w)};
    *(uint2*)(out + (size_t)i * 4) = *(const uint2*)h;
}

// W[K][N] fp32 -> Wt[N][K] bf16
__global__ __launch_bounds__(256) void transpose_w(const float* __restrict__ W,
                                                   __hip_bfloat16* __restrict__ Wt,
                                                   int K, int N) {
    int i = blockIdx.x * 256 + threadIdx.x;
    if (i >= K * N) return;
    int k = i / N, n = i - k * N;
    Wt[(size_t)n * K + k] = __float2bfloat16(W[i]);
}

// --------- bf16 MFMA GEMM: C[M,NC](bf16) = A[M,K](bf16) @ Bt[NC,K]^T ---------
// 128x128 tile, BK=32, 256 threads (4 waves, 2x2), double-buffered LDS via
// global_load_lds width=16, XOR swizzle (slot ^= (row>>1)&3) on both sides.
template <int K>
__global__ __launch_bounds__(256) void gemm_mfma(
        const __hip_bfloat16* __restrict__ A,
        const __hip_bfloat16* __restrict__ Bt,
        __hip_bfloat16* __restrict__ C,
        int M, int NC) {
    constexpr int KS = K / 32;
    __shared__ __hip_bfloat16 Alds[2][128][32];
    __shared__ __hip_bfloat16 Blds[2][128][32];
    const int tid  = threadIdx.x;
    const int w    = tid >> 6;
    const int lane = tid & 63;
    const int wr   = w >> 1, wc = w & 1;
    const int bm = blockIdx.y * 128, bn = blockIdx.x * 128;

    auto stage = [&](int t, int b) {
        const int k0 = t * 32;
#pragma unroll
        for (int i = 0; i < 2; ++i) {
            int ld    = (w << 1) | i;          // 0..7
            int rrel0 = ld << 4;               // 16-row group
            int rrel  = rrel0 + (lane >> 2);
            int slot  = lane & 3;
            int cg    = ((slot ^ ((rrel >> 1) & 3)) << 3);  // pre-swizzled col grp
            int arow  = bm + rrel; arow = arow < M ? arow : M - 1;
            GLOAD_LDS16(A  + (size_t)arow * K + k0 + cg, &Alds[b][rrel0][0]);
            int brow  = bn + rrel;             // NC multiple of 128 -> in range
            GLOAD_LDS16(Bt + (size_t)brow * K + k0 + cg, &Blds[b][rrel0][0]);
        }
    };

    f32x4 acc[4][4] = {};
    stage(0, 0);
    __syncthreads();                           // drains vmcnt before reads

    const int fr = lane & 15, fq = lane >> 4;
    for (int t = 0; t < KS; ++t) {
        const int b = t & 1;
        if (t + 1 < KS) stage(t + 1, b ^ 1);
        frag af[4], bf[4];
#pragma unroll
        for (int mf = 0; mf < 4; ++mf) {
            int arel = (wr << 6) + (mf << 4) + fr;
            int p = fq ^ ((arel >> 1) & 3);
            af[mf] = *(const frag*)&Alds[b][arel][p << 3];
        }
#pragma unroll
        for (int nf = 0; nf < 4; ++nf) {
            int nrel = (wc << 6) + (nf << 4) + fr;
            int p = fq ^ ((nrel >> 1) & 3);
            bf[nf] = *(const frag*)&Blds[b][nrel][p << 3];
        }
#pragma unroll
        for (int mf = 0; mf < 4; ++mf)
#pragma unroll
            for (int nf = 0; nf < 4; ++nf)
                acc[mf][nf] = __builtin_amdgcn_mfma_f32_16x16x32_bf16(
                    af[mf], bf[nf], acc[mf][nf], 0, 0, 0);
        __syncthreads();                       // also drains next-stage vmcnt
    }

    // C/D layout: col = lane&15, row = (lane>>4)*4 + reg   [m89-verified]
#pragma unroll
    for (int mf = 0; mf < 4; ++mf)
#pragma unroll
        for (int r = 0; r < 4; ++r) {
            int row = bm + (wr << 6) + (mf << 4) + (fq << 2) + r;
            if (row < M) {
#pragma unroll
                for (int nf = 0; nf < 4; ++nf) {
                    int col = bn + (wc << 6) + (nf << 4) + fr;
                    C[(size_t)row * NC + col] = __float2bfloat16(acc[mf][nf][r]);
                }
            }
        }
}

// ---------------- CSR build ----------------
__global__ void count_deg(const int* __restrict__ ei, int E, int Etot,
                          int* __restrict__ deg) {
    int e = blockIdx.x * blockDim.x + threadIdx.x;
    if (e >= Etot) return;
    int d = (e < E) ? ei[E + e] : (e - E);   // self-loop for e >= E
    atomicAdd(&deg[d], 1);
}

// three-phase exclusive scan: per-block scan, wave-scan of partials, add-back
__global__ __launch_bounds__(1024) void scan1(const int* __restrict__ deg,
                                              int* __restrict__ pre,
                                              int* __restrict__ bsum, int n) {
    __shared__ int buf[1024];
    int t = threadIdx.x;
    int i = blockIdx.x * 1024 + t;
    int v = (i < n) ? deg[i] : 0;
    buf[t] = v;
    __syncthreads();
#pragma unroll
    for (int off = 1; off < 1024; off <<= 1) {
        int xv = (t >= off) ? buf[t - off] : 0;
        __syncthreads();
        buf[t] += xv;
        __syncthreads();
    }
    if (i < n) pre[i] = buf[t] - v;          // exclusive within block
    if (t == 1023) bsum[blockIdx.x] = buf[1023];
}

__global__ void scan2(int* __restrict__ bsum, int nb) {   // nb <= 64, 1 wave
    int t = threadIdx.x;
    int v = (t < nb) ? bsum[t] : 0;
    int s = v;
#pragma unroll
    for (int off = 1; off < 64; off <<= 1) {
        int u = __shfl_up(s, off, 64);
        if (t >= off) s += u;
    }
    if (t < nb) bsum[t] = s - v;             // exclusive
}

__global__ __launch_bounds__(256) void scan3(const int* __restrict__ pre,
                                             const int* __restrict__ bsum,
                                             int* __restrict__ rowptr,
                                             int n, int Etot) {
    int i = blockIdx.x * 256 + threadIdx.x;
    if (i < n) rowptr[i] = pre[i] + bsum[i >> 10];
    if (i == 0) rowptr[n] = Etot;
}

__global__ void fill_csr(const int* __restrict__ ei, int E, int Etot,
                         const int* __restrict__ rowptr, int* __restrict__ cursor,
                         int* __restrict__ csrc) {
    int e = blockIdx.x * blockDim.x + threadIdx.x;
    if (e >= Etot) return;
    int s, d;
    if (e < E) { s = ei[e]; d = ei[E + e]; }
    else       { s = e - E; d = s; }
    int pos = rowptr[d] + atomicAdd(&cursor[d], 1);
    csrc[pos] = s;
}

// -------- bf16 row fragment -> fp32 registers --------
template <int CPL>
__device__ __forceinline__ void bload(float* d, const __hip_bfloat16* p) {
    if constexpr (CPL == 4) {
        uint2 u = *(const uint2*)p;
        d[0] = __uint_as_float(u.x << 16);
        d[1] = __uint_as_float(u.x & 0xffff0000u);
        d[2] = __uint_as_float(u.y << 16);
        d[3] = __uint_as_float(u.y & 0xffff0000u);
    } else {
        unsigned u = *(const unsigned*)p;
        d[0] = __uint_as_float(u << 16);
        d[1] = __uint_as_float(u & 0xffff0000u);
    }
}

template <int CPL, typename OutT>
__device__ __forceinline__ void store_out(OutT* p, const float* v) {
    if constexpr (sizeof(OutT) == 2) {
        __hip_bfloat16 h[CPL];
#pragma unroll
        for (int j = 0; j < CPL; ++j) h[j] = __float2bfloat16(v[j]);
        if constexpr (CPL == 4) *(uint2*)p = *(const uint2*)h;
        else                    *(unsigned*)p = *(const unsigned*)h;
    } else {
        if constexpr (CPL == 4) *(float4*)p = *(const float4*)v;
        else                    *(float2*)p = *(const float2*)v;
    }
}

// ---- fused GATv2 attention + aggregate: one wave per node, defer-max softmax,
// 4-edge batches for ILP on the {gather, shuffle-reduce, exp} latency chain.
// XLR[N][S]: XL = cols 0..C-1, XR = cols C..2C-1.
template <int C, int H, int S, typename OutT>
__global__ __launch_bounds__(256) void gat_agg(
        const __hip_bfloat16* __restrict__ XLR,
        const int* __restrict__ rowptr, const int* __restrict__ csrc,
        const float* __restrict__ att, const float* __restrict__ bias,
        OutT* __restrict__ OUT, int N) {
    constexpr int CPL = C / 64;
    constexpr int LPH = 64 / H;     // lanes per head
    int node = (blockIdx.x * blockDim.x + threadIdx.x) >> 6;
    int lane = threadIdx.x & 63;
    if (node >= N) return;
    int ch0 = lane * CPL;

    float attv[CPL], attv5[CPL], xrv[CPL];
    bload<CPL>(xrv, XLR + (size_t)node * S + C + ch0);
#pragma unroll
    for (int j = 0; j < CPL; ++j) {
        attv[j]  = att[ch0 + j];
        attv5[j] = attv[j] * NEG_SLOPE;
    }

    float m = -INFINITY, sumw = 0.f;
    float acc[CPL];
#pragma unroll
    for (int j = 0; j < CPL; ++j) acc[j] = 0.f;

    const int e0 = rowptr[node], e1 = rowptr[node + 1];  // deg >= 1 (self-loop)

    float cur[4][CPL], nxt[4][CPL];
    // load a batch of 4 rows, clamped (invalid edges masked later via l=-inf)
    auto ldrow = [&](float (*dst)[CPL], int k) {
#pragma unroll
        for (int i = 0; i < 4; ++i) {
            int kk = k + i; kk = kk < e1 - 1 ? kk : e1 - 1;
            bload<CPL>(dst[i], XLR + (size_t)csrc[kk] * S + ch0);
        }
    };
    ldrow(cur, e0);

    for (int k = e0; k < e1; k += 4) {
        bool more = (k + 4) < e1;              // wave-uniform
        if (more) ldrow(nxt, k + 4);           // prefetch next batch

        float l[4];
#pragma unroll
        for (int i = 0; i < 4; ++i) {
            float partial = 0.f;
#pragma unroll
            for (int j = 0; j < CPL; ++j) {
                float v = cur[i][j] + xrv[j];
                partial = fmaf(v, v > 0.f ? attv[j] : attv5[j], partial);
            }
#pragma unroll
            for (int off = 1; off < LPH; off <<= 1)
                partial += __shfl_xor(partial, off, 64);
            l[i] = (k + i < e1) ? partial : -INFINITY;
        }

        float lmax = fmaxf(fmaxf(l[0], l[1]), fmaxf(l[2], l[3]));
        // defer-max: rescale only when base grows by > 8; first batch
        // (m=-inf) self-initializes since exp(-inf)=0 zeroes empty history.
        if (lmax > m + 8.f) {
            float rs = __expf(m - lmax);
            sumw *= rs;
#pragma unroll
            for (int j = 0; j < CPL; ++j) acc[j] *= rs;
            m = lmax;
        }
        float w0 = __expf(l[0] - m), w1 = __expf(l[1] - m);
        float w2 = __expf(l[2] - m), w3 = __expf(l[3] - m);
        sumw += (w0 + w1) + (w2 + w3);
#pragma unroll
        for (int j = 0; j < CPL; ++j)
            acc[j] = fmaf(w0, cur[0][j],
                     fmaf(w1, cur[1][j],
                     fmaf(w2, cur[2][j],
                     fmaf(w3, cur[3][j], acc[j]))));

        if (more) {
#pragma unroll
            for (int i = 0; i < 4; ++i)
#pragma unroll
                for (int j = 0; j < CPL; ++j) cur[i][j] = nxt[i][j];
        }
    }
    float inv = 1.f / sumw;
    float o[CPL];
#pragma unroll
    for (int j = 0; j < CPL; ++j)
        o[j] = fmaf(acc[j], inv, bias[ch0 + j]);
    store_out<CPL>(OUT + (size_t)node * C + ch0, o);
}

// ---------------- batchnorm (bf16 I/O, fp32 math) ----------------
__global__ __launch_bounds__(256) void bn_stats(const __hip_bfloat16* __restrict__ Hm,
        float* __restrict__ sums, float* __restrict__ sqs, int N, int C) {
    int ch = threadIdx.x;               // C == 256 == blockDim.x
    int r0 = blockIdx.x * 256;
    int r1 = min(N, r0 + 256);
    float s = 0.f, q = 0.f;
    for (int r = r0; r < r1; ++r) {
        float v = __bfloat162float(Hm[(size_t)r * C + ch]);
        s += v;
        q = fmaf(v, v, q);
    }
    atomicAdd(&sums[ch], s);
    atomicAdd(&sqs[ch], q);
}

__global__ __launch_bounds__(256) void bn_elu(const __hip_bfloat16* __restrict__ Hm,
        __hip_bfloat16* __restrict__ Ob,
        const float* __restrict__ sums, const float* __restrict__ sqs,
        const float* __restrict__ gamma, const float* __restrict__ beta,
        int total, int C, float invN) {
    int idx = blockIdx.x * 256 + threadIdx.x;
    if (idx >= total) return;
    int ch = idx & (C - 1);
    float mu = sums[ch] * invN;
    float var = sqs[ch] * invN - mu * mu;
    float sc = gamma[ch] * rsqrtf(var + BN_EPS);
    float v = (__bfloat162float(Hm[idx]) - mu) * sc + beta[ch];
    v = v > 0.f ? v : expm1f(v);
    Ob[idx] = __float2bfloat16(v);
}

extern "C" void kernel_launch(void* const* d_in, const int* in_sizes, int n_in,
                              void* d_out, int out_size, void* d_ws, size_t ws_size,
                              hipStream_t stream) {
    const float* x    = (const float*)d_in[0];
    const int*   ei   = (const int*)d_in[1];
    const float* Wl1  = (const float*)d_in[2];
    const float* Wr1  = (const float*)d_in[3];
    const float* att1 = (const float*)d_in[4];
    const float* b1   = (const float*)d_in[5];
    const float* g1   = (const float*)d_in[6];
    const float* be1  = (const float*)d_in[7];
    const float* Wl2  = (const float*)d_in[8];
    const float* Wr2  = (const float*)d_in[9];
    const float* att2 = (const float*)d_in[10];
    const float* b2   = (const float*)d_in[11];
    const float* g2   = (const float*)d_in[12];
    const float* be2  = (const float*)d_in[13];
    const float* Wl3  = (const float*)d_in[14];
    const float* Wr3  = (const float*)d_in[15];
    const float* att3 = (const float*)d_in[16];
    const float* b3   = (const float*)d_in[17];
    float* out = (float*)d_out;

    const int IN_F = 128, HC = 256, OUT_F = 128;
    const int N = in_sizes[0] / IN_F;     // 50000
    const int E = in_sizes[1] / 2;        // 800000
    const int Etot = E + N;               // 850000

    // ---- workspace carve-up ----
    char* p = (char*)d_ws;
    auto alloc = [&](size_t bytes) {
        void* r = (void*)p;
        p += (bytes + 255) & ~(size_t)255;
        return r;
    };
    __hip_bfloat16* XLR  = (__hip_bfloat16*)alloc((size_t)N * 2 * HC * 2);  // [N][512]
    __hip_bfloat16* Hb   = (__hip_bfloat16*)alloc((size_t)N * HC * 2);
    __hip_bfloat16* Hbb  = (__hip_bfloat16*)alloc((size_t)N * HC * 2);
    __hip_bfloat16* xbf  = (__hip_bfloat16*)alloc((size_t)N * IN_F * 2);
    __hip_bfloat16* Wc1  = (__hip_bfloat16*)alloc((size_t)2 * HC * IN_F * 2);   // [512][128]
    __hip_bfloat16* Wc2  = (__hip_bfloat16*)alloc((size_t)2 * HC * HC * 2);     // [512][256]
    __hip_bfloat16* Wc3  = (__hip_bfloat16*)alloc((size_t)2 * OUT_F * HC * 2);  // [256][256]
    int* deg       = (int*)alloc((size_t)N * 4);
    int* pre       = (int*)alloc((size_t)N * 4);
    int* bsum      = (int*)alloc(64 * 4);
    int* rowptr    = (int*)alloc((size_t)(N + 1) * 4);
    int* cursor    = (int*)alloc((size_t)N * 4);
    int* csrc      = (int*)alloc((size_t)Etot * 4);
    float* bns     = (float*)alloc((size_t)HC * 4);
    float* bnq     = (float*)alloc((size_t)HC * 4);

    const int eb = (Etot + 255) / 256;
    const int nb = (N + 3) / 4;
    const int gemmRows = (N + 127) / 128;
    const int scanB = (N + 1023) / 1024;

    // ---- one-time conversions (weights concatenated [Wl; Wr] transposed) ----
    f32_to_bf16<<<(N * IN_F / 4 + 255) / 256, 256, 0, stream>>>(x, xbf, N * IN_F / 4);
    transpose_w<<<(IN_F * HC + 255) / 256, 256, 0, stream>>>(Wl1, Wc1, IN_F, HC);
    transpose_w<<<(IN_F * HC + 255) / 256, 256, 0, stream>>>(Wr1, Wc1 + (size_t)HC * IN_F, IN_F, HC);
    transpose_w<<<(HC * HC + 255) / 256, 256, 0, stream>>>(Wl2, Wc2, HC, HC);
    transpose_w<<<(HC * HC + 255) / 256, 256, 0, stream>>>(Wr2, Wc2 + (size_t)HC * HC, HC, HC);
    transpose_w<<<(HC * OUT_F + 255) / 256, 256, 0, stream>>>(Wl3, Wc3, HC, OUT_F);
    transpose_w<<<(HC * OUT_F + 255) / 256, 256, 0, stream>>>(Wr3, Wc3 + (size_t)OUT_F * HC, HC, OUT_F);

    // ---- CSR by dst (built once, reused by all 3 layers) ----
    hipMemsetAsync(deg, 0, (size_t)N * 4, stream);
    count_deg<<<eb, 256, 0, stream>>>(ei, E, Etot, deg);
    scan1<<<scanB, 1024, 0, stream>>>(deg, pre, bsum, N);
    scan2<<<1, 64, 0, stream>>>(bsum, scanB);
    scan3<<<(N + 255) / 256, 256, 0, stream>>>(pre, bsum, rowptr, N, Etot);
    hipMemsetAsync(cursor, 0, (size_t)N * 4, stream);
    fill_csr<<<eb, 256, 0, stream>>>(ei, E, Etot, rowptr, cursor, csrc);

    // ================= Layer 1 (K=128): one GEMM -> XLR[N][512] =============
    gemm_mfma<128><<<dim3(4, gemmRows), 256, 0, stream>>>(xbf, Wc1, XLR, N, 2 * HC);
    gat_agg<256, 4, 512><<<nb, 256, 0, stream>>>(XLR, rowptr, csrc, att1, b1, Hb, N);
    hipMemsetAsync(bns, 0, HC * 4, stream);
    hipMemsetAsync(bnq, 0, HC * 4, stream);
    bn_stats<<<(N + 255) / 256, 256, 0, stream>>>(Hb, bns, bnq, N, HC);
    bn_elu<<<(N * HC + 255) / 256, 256, 0, stream>>>(Hb, Hbb, bns, bnq, g1, be1, N * HC, HC, 1.f / N);

    // ================= Layer 2 (K=256) ======================================
    gemm_mfma<256><<<dim3(4, gemmRows), 256, 0, stream>>>(Hbb, Wc2, XLR, N, 2 * HC);
    gat_agg<256, 4, 512><<<nb, 256, 0, stream>>>(XLR, rowptr, csrc, att2, b2, Hb, N);
    hipMemsetAsync(bns, 0, HC * 4, stream);
    hipMemsetAsync(bnq, 0, HC * 4, stream);
    bn_stats<<<(N + 255) / 256, 256, 0, stream>>>(Hb, bns, bnq, N, HC);
    bn_elu<<<(N * HC + 255) / 256, 256, 0, stream>>>(Hb, Hbb, bns, bnq, g2, be2, N * HC, HC, 1.f / N);

    // ================= Layer 3 (K=256, 1 head, 128 ch) ======================
    gemm_mfma<256><<<dim3(2, gemmRows), 256, 0, stream>>>(Hbb, Wc3, XLR, N, 2 * OUT_F);
    gat_agg<128, 1, 256><<<nb, 256, 0, stream>>>(XLR, rowptr, csrc, att3, b3, out, N);
}

// Round 6
// 585.140 us; speedup vs baseline: 3.0046x; 1.0094x over previous
//
#include <hip/hip_runtime.h>
#include <hip/hip_bf16.h>
#include <math.h>

#define NEG_SLOPE 0.2f
#define BN_EPS 1e-5f

using frag  = __attribute__((ext_vector_type(8))) short;   // 8 x bf16
using f32x4 = __attribute__((ext_vector_type(4))) float;
using f32x2 = __attribute__((ext_vector_type(2))) float;   // -> v_pk_* ops

#define GLOAD_LDS16(gp, lp) __builtin_amdgcn_global_load_lds( \
    (const __attribute__((address_space(1))) void*)(gp),      \
    (__attribute__((address_space(3))) void*)(lp), 16, 0, 0)

// ---------------- conversions ----------------
__global__ __launch_bounds__(256) void f32_to_bf16(const float* __restrict__ in,
                                                   __hip_bfloat16* __restrict__ out,
                                                   int n4) {   // n4 = n/4
    int i = blockIdx.x * 256 + threadIdx.x;
    if (i >= n4) return;
    float4 v = *(const float4*)(in + (size_t)i * 4);
    __hip_bfloat16 h[4] = {__float2bfloat16(v.x), __float2bfloat16(v.y),
                           __float2bfloat16(v.z), __float2bfloat16(v.w)};
    *(uint2*)(out + (size_t)i * 4) = *(const uint2*)h;
}

// W[K][N] fp32 -> Wt[N][K] bf16
__global__ __launch_bounds__(256) void transpose_w(const float* __restrict__ W,
                                                   __hip_bfloat16* __restrict__ Wt,
                                                   int K, int N) {
    int i = blockIdx.x * 256 + threadIdx.x;
    if (i >= K * N) return;
    int k = i / N, n = i - k * N;
    Wt[(size_t)n * K + k] = __float2bfloat16(W[i]);
}

// --------- bf16 MFMA GEMM: C[M,NC](bf16) = A[M,K](bf16) @ Bt[NC,K]^T ---------
template <int K>
__global__ __launch_bounds__(256) void gemm_mfma(
        const __hip_bfloat16* __restrict__ A,
        const __hip_bfloat16* __restrict__ Bt,
        __hip_bfloat16* __restrict__ C,
        int M, int NC) {
    constexpr int KS = K / 32;
    __shared__ __hip_bfloat16 Alds[2][128][32];
    __shared__ __hip_bfloat16 Blds[2][128][32];
    const int tid  = threadIdx.x;
    const int w    = tid >> 6;
    const int lane = tid & 63;
    const int wr   = w >> 1, wc = w & 1;
    const int bm = blockIdx.y * 128, bn = blockIdx.x * 128;

    auto stage = [&](int t, int b) {
        const int k0 = t * 32;
#pragma unroll
        for (int i = 0; i < 2; ++i) {
            int ld    = (w << 1) | i;          // 0..7
            int rrel0 = ld << 4;               // 16-row group
            int rrel  = rrel0 + (lane >> 2);
            int slot  = lane & 3;
            int cg    = ((slot ^ ((rrel >> 1) & 3)) << 3);  // pre-swizzled col grp
            int arow  = bm + rrel; arow = arow < M ? arow : M - 1;
            GLOAD_LDS16(A  + (size_t)arow * K + k0 + cg, &Alds[b][rrel0][0]);
            int brow  = bn + rrel;             // NC multiple of 128 -> in range
            GLOAD_LDS16(Bt + (size_t)brow * K + k0 + cg, &Blds[b][rrel0][0]);
        }
    };

    f32x4 acc[4][4] = {};
    stage(0, 0);
    __syncthreads();                           // drains vmcnt before reads

    const int fr = lane & 15, fq = lane >> 4;
    for (int t = 0; t < KS; ++t) {
        const int b = t & 1;
        if (t + 1 < KS) stage(t + 1, b ^ 1);
        frag af[4], bf[4];
#pragma unroll
        for (int mf = 0; mf < 4; ++mf) {
            int arel = (wr << 6) + (mf << 4) + fr;
            int p = fq ^ ((arel >> 1) & 3);
            af[mf] = *(const frag*)&Alds[b][arel][p << 3];
        }
#pragma unroll
        for (int nf = 0; nf < 4; ++nf) {
            int nrel = (wc << 6) + (nf << 4) + fr;
            int p = fq ^ ((nrel >> 1) & 3);
            bf[nf] = *(const frag*)&Blds[b][nrel][p << 3];
        }
#pragma unroll
        for (int mf = 0; mf < 4; ++mf)
#pragma unroll
            for (int nf = 0; nf < 4; ++nf)
                acc[mf][nf] = __builtin_amdgcn_mfma_f32_16x16x32_bf16(
                    af[mf], bf[nf], acc[mf][nf], 0, 0, 0);
        __syncthreads();                       // also drains next-stage vmcnt
    }

    // C/D layout: col = lane&15, row = (lane>>4)*4 + reg   [m89-verified]
#pragma unroll
    for (int mf = 0; mf < 4; ++mf)
#pragma unroll
        for (int r = 0; r < 4; ++r) {
            int row = bm + (wr << 6) + (mf << 4) + (fq << 2) + r;
            if (row < M) {
#pragma unroll
                for (int nf = 0; nf < 4; ++nf) {
                    int col = bn + (wc << 6) + (nf << 4) + fr;
                    C[(size_t)row * NC + col] = __float2bfloat16(acc[mf][nf][r]);
                }
            }
        }
}

// ---------------- CSR build (rows padded to multiples of 4) ----------------
__global__ void count_deg(const int* __restrict__ ei, int E, int Etot,
                          int* __restrict__ deg) {
    int e = blockIdx.x * blockDim.x + threadIdx.x;
    if (e >= Etot) return;
    int d = (e < E) ? ei[E + e] : (e - E);   // self-loop for e >= E
    atomicAdd(&deg[d], 1);
}

// scan of PADDED degrees: per-block scan, wave-scan of partials, add-back
__global__ __launch_bounds__(1024) void scan1(const int* __restrict__ deg,
                                              int* __restrict__ pre,
                                              int* __restrict__ bsum, int n) {
    __shared__ int buf[1024];
    int t = threadIdx.x;
    int i = blockIdx.x * 1024 + t;
    int v = (i < n) ? ((deg[i] + 3) & ~3) : 0;   // padded degree
    buf[t] = v;
    __syncthreads();
#pragma unroll
    for (int off = 1; off < 1024; off <<= 1) {
        int xv = (t >= off) ? buf[t - off] : 0;
        __syncthreads();
        buf[t] += xv;
        __syncthreads();
    }
    if (i < n) pre[i] = buf[t] - v;          // exclusive within block
    if (t == 1023) bsum[blockIdx.x] = buf[1023];
}

__global__ void scan2(int* __restrict__ bsum, int nb) {   // nb <= 64, 1 wave
    int t = threadIdx.x;
    int v = (t < nb) ? bsum[t] : 0;
    int s = v;
#pragma unroll
    for (int off = 1; off < 64; off <<= 1) {
        int u = __shfl_up(s, off, 64);
        if (t >= off) s += u;
    }
    if (t < nb) bsum[t] = s - v;             // exclusive
}

__global__ __launch_bounds__(256) void scan3(const int* __restrict__ pre,
                                             const int* __restrict__ bsum,
                                             int* __restrict__ rowptr, int n) {
    int i = blockIdx.x * 256 + threadIdx.x;
    if (i < n) rowptr[i] = pre[i] + bsum[i >> 10];
}

__global__ void fill_csr(const int* __restrict__ ei, int E, int Etot,
                         const int* __restrict__ rowptr, int* __restrict__ cursor,
                         int* __restrict__ csrc) {
    int e = blockIdx.x * blockDim.x + threadIdx.x;
    if (e >= Etot) return;
    int s, d;
    if (e < E) { s = ei[e]; d = ei[E + e]; }
    else       { s = e - E; d = s; }
    int pos = rowptr[d] + atomicAdd(&cursor[d], 1);
    csrc[pos] = s;
}

template <int CPL, typename OutT>
__device__ __forceinline__ void store_out(OutT* p, const float* v) {
    if constexpr (sizeof(OutT) == 2) {
        __hip_bfloat16 h[CPL];
#pragma unroll
        for (int j = 0; j < CPL; ++j) h[j] = __float2bfloat16(v[j]);
        if constexpr (CPL == 4) *(uint2*)p = *(const uint2*)h;
        else                    *(unsigned*)p = *(const unsigned*)h;
    } else {
        if constexpr (CPL == 4) *(float4*)p = *(const float4*)v;
        else                    *(float2*)p = *(const float2*)v;
    }
}

// ---- fused GATv2 attention + aggregate: one wave per node, defer-max softmax,
// 4-edge aligned batches (padded CSR), packed-fp32 math, ping-pong prefetch.
// XLR[N][S]: XL = cols 0..C-1, XR = cols C..2C-1.
template <int C, int H, int S, typename OutT>
__global__ __launch_bounds__(256) void gat_agg(
        const __hip_bfloat16* __restrict__ XLR,
        const int* __restrict__ rowptr, const int* __restrict__ deg,
        const int4* __restrict__ csrc4,
        const float* __restrict__ att, const float* __restrict__ bias,
        OutT* __restrict__ OUT, int N) {
    constexpr int CPL = C / 64;          // channels per lane (4 or 2)
    constexpr int NP  = CPL / 2;         // float2 pairs per lane
    constexpr int LPH = 64 / H;          // lanes per head
    const int node = (blockIdx.x * blockDim.x + threadIdx.x) >> 6;
    const int lane = threadIdx.x & 63;
    if (node >= N) return;
    const unsigned ch0 = lane * CPL;

    // leaky(v)*att == (0.6*att)*v + (0.4*att)*|v|   (NEG_SLOPE = 0.2)
    f32x2 xr2[NP], c1[NP], c2[NP];
    {
        const __hip_bfloat16* xr = XLR + (size_t)node * S + C + ch0;
#pragma unroll
        for (int p = 0; p < NP; ++p) {
            unsigned u = ((const unsigned*)xr)[p];
            xr2[p] = f32x2{__uint_as_float(u << 16),
                           __uint_as_float(u & 0xffff0000u)};
            float a0 = att[ch0 + 2 * p], a1 = att[ch0 + 2 * p + 1];
            c1[p] = f32x2{0.6f * a0, 0.6f * a1};
            c2[p] = f32x2{0.4f * a0, 0.4f * a1};
        }
    }

    const int e0  = rowptr[node];
    const int dg  = deg[node];           // true degree (>=1, self-loop)
    const int e1  = e0 + dg;
    const int nb4 = (dg + 3) >> 2;       // padded batches
    const int4* cb = csrc4 + (e0 >> 2);  // e0 is a multiple of 4

    float m = -INFINITY, sumw = 0.f;
    f32x2 acc2[NP] = {};

    // 32-bit element offsets (max idx*S + ch0 < 2^31)
    auto ldrow4 = [&](f32x2 (*dst)[NP], int4 idx) {
        int ids[4] = {idx.x, idx.y, idx.z, idx.w};
#pragma unroll
        for (int i = 0; i < 4; ++i) {
            unsigned off = (unsigned)ids[i] * (unsigned)S + ch0;
            if constexpr (NP == 2) {
                uint2 u = *(const uint2*)(XLR + off);
                dst[i][0] = f32x2{__uint_as_float(u.x << 16),
                                  __uint_as_float(u.x & 0xffff0000u)};
                dst[i][1] = f32x2{__uint_as_float(u.y << 16),
                                  __uint_as_float(u.y & 0xffff0000u)};
            } else {
                unsigned u = *(const unsigned*)(XLR + off);
                dst[i][0] = f32x2{__uint_as_float(u << 16),
                                  __uint_as_float(u & 0xffff0000u)};
            }
        }
    };

    auto process = [&](f32x2 (*xl)[NP], int k) {
        float l[4];
#pragma unroll
        for (int i = 0; i < 4; ++i) {
            f32x2 s1 = {0.f, 0.f}, s2 = {0.f, 0.f};
#pragma unroll
            for (int p = 0; p < NP; ++p) {
                f32x2 v  = xl[i][p] + xr2[p];                 // v_pk_add_f32
                f32x2 av = f32x2{__builtin_fabsf(v.x), __builtin_fabsf(v.y)};
                s1 = c1[p] * v  + s1;                         // v_pk_fma_f32
                s2 = c2[p] * av + s2;
            }
            f32x2 s = s1 + s2;
            float partial = s.x + s.y;
#pragma unroll
            for (int off = 1; off < LPH; off <<= 1)
                partial += __shfl_xor(partial, off, 64);
            l[i] = partial;
        }
        if (e1 - k < 4) {                                     // uniform tail mask
#pragma unroll
            for (int i = 0; i < 4; ++i)
                if (k + i >= e1) l[i] = -INFINITY;
        }
        float lmax = fmaxf(fmaxf(l[0], l[1]), fmaxf(l[2], l[3]));
        // defer-max: rescale only on >8 growth; first batch self-initializes
        if (lmax > m + 8.f) {
            float rs = __expf(m - lmax);
            f32x2 rs2 = {rs, rs};
            sumw *= rs;
#pragma unroll
            for (int p = 0; p < NP; ++p) acc2[p] *= rs2;
            m = lmax;
        }
        float w0 = __expf(l[0] - m), w1 = __expf(l[1] - m);
        float w2 = __expf(l[2] - m), w3 = __expf(l[3] - m);
        sumw += (w0 + w1) + (w2 + w3);
        f32x2 v0 = {w0, w0}, v1 = {w1, w1}, v2 = {w2, w2}, v3 = {w3, w3};
#pragma unroll
        for (int p = 0; p < NP; ++p) {
            f32x2 a = acc2[p];
            a = v0 * xl[0][p] + a;
            a = v1 * xl[1][p] + a;
            a = v2 * xl[2][p] + a;
            a = v3 * xl[3][p] + a;
            acc2[p] = a;
        }
    };

    f32x2 bufA[4][NP], bufB[4][NP];
    int4 idxA = cb[0], idxB;
    ldrow4(bufA, idxA);
    if (nb4 > 1) idxB = cb[1];

    int bi = 0, k = e0;
    while (true) {
        // process bufA (batch bi); prefetch rows bi+1 (idxB), idx bi+2 -> idxA
        if (bi + 1 < nb4) ldrow4(bufB, idxB);
        if (bi + 2 < nb4) idxA = cb[bi + 2];
        process(bufA, k);
        ++bi; k += 4;
        if (bi >= nb4) break;
        // process bufB (batch bi); prefetch rows bi+1 (idxA), idx bi+2 -> idxB
        if (bi + 1 < nb4) ldrow4(bufA, idxA);
        if (bi + 2 < nb4) idxB = cb[bi + 2];
        process(bufB, k);
        ++bi; k += 4;
        if (bi >= nb4) break;
    }

    float inv = 1.f / sumw;
    float o[CPL];
#pragma unroll
    for (int p = 0; p < NP; ++p) {
        o[2 * p]     = fmaf(acc2[p].x, inv, bias[ch0 + 2 * p]);
        o[2 * p + 1] = fmaf(acc2[p].y, inv, bias[ch0 + 2 * p + 1]);
    }
    store_out<CPL>(OUT + (size_t)node * C + ch0, o);
}

// ---------------- batchnorm (bf16 I/O, fp32 math) ----------------
__global__ __launch_bounds__(256) void bn_stats(const __hip_bfloat16* __restrict__ Hm,
        float* __restrict__ sums, float* __restrict__ sqs, int N, int C) {
    int ch = threadIdx.x;               // C == 256 == blockDim.x
    int r0 = blockIdx.x * 256;
    int r1 = min(N, r0 + 256);
    float s = 0.f, q = 0.f;
    for (int r = r0; r < r1; ++r) {
        float v = __bfloat162float(Hm[(size_t)r * C + ch]);
        s += v;
        q = fmaf(v, v, q);
    }
    atomicAdd(&sums[ch], s);
    atomicAdd(&sqs[ch], q);
}

__global__ __launch_bounds__(256) void bn_elu(const __hip_bfloat16* __restrict__ Hm,
        __hip_bfloat16* __restrict__ Ob,
        const float* __restrict__ sums, const float* __restrict__ sqs,
        const float* __restrict__ gamma, const float* __restrict__ beta,
        int total, int C, float invN) {
    int idx = blockIdx.x * 256 + threadIdx.x;
    if (idx >= total) return;
    int ch = idx & (C - 1);
    float mu = sums[ch] * invN;
    float var = sqs[ch] * invN - mu * mu;
    float sc = gamma[ch] * rsqrtf(var + BN_EPS);
    float v = (__bfloat162float(Hm[idx]) - mu) * sc + beta[ch];
    v = v > 0.f ? v : expm1f(v);
    Ob[idx] = __float2bfloat16(v);
}

extern "C" void kernel_launch(void* const* d_in, const int* in_sizes, int n_in,
                              void* d_out, int out_size, void* d_ws, size_t ws_size,
                              hipStream_t stream) {
    const float* x    = (const float*)d_in[0];
    const int*   ei   = (const int*)d_in[1];
    const float* Wl1  = (const float*)d_in[2];
    const float* Wr1  = (const float*)d_in[3];
    const float* att1 = (const float*)d_in[4];
    const float* b1   = (const float*)d_in[5];
    const float* g1   = (const float*)d_in[6];
    const float* be1  = (const float*)d_in[7];
    const float* Wl2  = (const float*)d_in[8];
    const float* Wr2  = (const float*)d_in[9];
    const float* att2 = (const float*)d_in[10];
    const float* b2   = (const float*)d_in[11];
    const float* g2   = (const float*)d_in[12];
    const float* be2  = (const float*)d_in[13];
    const float* Wl3  = (const float*)d_in[14];
    const float* Wr3  = (const float*)d_in[15];
    const float* att3 = (const float*)d_in[16];
    const float* b3   = (const float*)d_in[17];
    float* out = (float*)d_out;

    const int IN_F = 128, HC = 256, OUT_F = 128;
    const int N = in_sizes[0] / IN_F;     // 50000
    const int E = in_sizes[1] / 2;        // 800000
    const int Etot = E + N;               // 850000
    const int EP = Etot + 3 * N;          // padded-CSR capacity bound

    // ---- workspace carve-up ----
    char* p = (char*)d_ws;
    auto alloc = [&](size_t bytes) {
        void* r = (void*)p;
        p += (bytes + 255) & ~(size_t)255;
        return r;
    };
    __hip_bfloat16* XLR  = (__hip_bfloat16*)alloc((size_t)N * 2 * HC * 2);  // [N][512]
    __hip_bfloat16* Hb   = (__hip_bfloat16*)alloc((size_t)N * HC * 2);
    __hip_bfloat16* Hbb  = (__hip_bfloat16*)alloc((size_t)N * HC * 2);
    __hip_bfloat16* xbf  = (__hip_bfloat16*)alloc((size_t)N * IN_F * 2);
    __hip_bfloat16* Wc1  = (__hip_bfloat16*)alloc((size_t)2 * HC * IN_F * 2);   // [512][128]
    __hip_bfloat16* Wc2  = (__hip_bfloat16*)alloc((size_t)2 * HC * HC * 2);     // [512][256]
    __hip_bfloat16* Wc3  = (__hip_bfloat16*)alloc((size_t)2 * OUT_F * HC * 2);  // [256][256]
    int* deg       = (int*)alloc((size_t)N * 4);
    int* pre       = (int*)alloc((size_t)N * 4);
    int* bsum      = (int*)alloc(64 * 4);
    int* rowptr    = (int*)alloc((size_t)(N + 1) * 4);
    int* cursor    = (int*)alloc((size_t)N * 4);
    int* csrc      = (int*)alloc((size_t)EP * 4 + 16);
    float* bns     = (float*)alloc((size_t)HC * 4);
    float* bnq     = (float*)alloc((size_t)HC * 4);

    const int eb = (Etot + 255) / 256;
    const int nb = (N + 3) / 4;
    const int gemmRows = (N + 127) / 128;
    const int scanB = (N + 1023) / 1024;

    // ---- one-time conversions (weights concatenated [Wl; Wr] transposed) ----
    f32_to_bf16<<<(N * IN_F / 4 + 255) / 256, 256, 0, stream>>>(x, xbf, N * IN_F / 4);
    transpose_w<<<(IN_F * HC + 255) / 256, 256, 0, stream>>>(Wl1, Wc1, IN_F, HC);
    transpose_w<<<(IN_F * HC + 255) / 256, 256, 0, stream>>>(Wr1, Wc1 + (size_t)HC * IN_F, IN_F, HC);
    transpose_w<<<(HC * HC + 255) / 256, 256, 0, stream>>>(Wl2, Wc2, HC, HC);
    transpose_w<<<(HC * HC + 255) / 256, 256, 0, stream>>>(Wr2, Wc2 + (size_t)HC * HC, HC, HC);
    transpose_w<<<(HC * OUT_F + 255) / 256, 256, 0, stream>>>(Wl3, Wc3, HC, OUT_F);
    transpose_w<<<(HC * OUT_F + 255) / 256, 256, 0, stream>>>(Wr3, Wc3 + (size_t)OUT_F * HC, HC, OUT_F);

    // ---- padded CSR by dst (built once, reused by all 3 layers) ----
    hipMemsetAsync(deg, 0, (size_t)N * 4, stream);
    count_deg<<<eb, 256, 0, stream>>>(ei, E, Etot, deg);
    scan1<<<scanB, 1024, 0, stream>>>(deg, pre, bsum, N);
    scan2<<<1, 64, 0, stream>>>(bsum, scanB);
    scan3<<<(N + 255) / 256, 256, 0, stream>>>(pre, bsum, rowptr, N);
    hipMemsetAsync(cursor, 0, (size_t)N * 4, stream);
    hipMemsetAsync(csrc, 0, (size_t)EP * 4, stream);   // pad slots -> node 0 (masked)
    fill_csr<<<eb, 256, 0, stream>>>(ei, E, Etot, rowptr, cursor, csrc);

    // ================= Layer 1 (K=128): one GEMM -> XLR[N][512] =============
    gemm_mfma<128><<<dim3(4, gemmRows), 256, 0, stream>>>(xbf, Wc1, XLR, N, 2 * HC);
    gat_agg<256, 4, 512><<<nb, 256, 0, stream>>>(XLR, rowptr, deg, (const int4*)csrc, att1, b1, Hb, N);
    hipMemsetAsync(bns, 0, HC * 4, stream);
    hipMemsetAsync(bnq, 0, HC * 4, stream);
    bn_stats<<<(N + 255) / 256, 256, 0, stream>>>(Hb, bns, bnq, N, HC);
    bn_elu<<<(N * HC + 255) / 256, 256, 0, stream>>>(Hb, Hbb, bns, bnq, g1, be1, N * HC, HC, 1.f / N);

    // ================= Layer 2 (K=256) ======================================
    gemm_mfma<256><<<dim3(4, gemmRows), 256, 0, stream>>>(Hbb, Wc2, XLR, N, 2 * HC);
    gat_agg<256, 4, 512><<<nb, 256, 0, stream>>>(XLR, rowptr, deg, (const int4*)csrc, att2, b2, Hb, N);
    hipMemsetAsync(bns, 0, HC * 4, stream);
    hipMemsetAsync(bnq, 0, HC * 4, stream);
    bn_stats<<<(N + 255) / 256, 256, 0, stream>>>(Hb, bns, bnq, N, HC);
    bn_elu<<<(N * HC + 255) / 256, 256, 0, stream>>>(Hb, Hbb, bns, bnq, g2, be2, N * HC, HC, 1.f / N);

    // ================= Layer 3 (K=256, 1 head, 128 ch) ======================
    gemm_mfma<256><<<dim3(2, gemmRows), 256, 0, stream>>>(Hbb, Wc3, XLR, N, 2 * OUT_F);
    gat_agg<128, 1, 256><<<nb, 256, 0, stream>>>(XLR, rowptr, deg, (const int4*)csrc, att3, b3, out, N);
}